// Round 3
// baseline (757.063 us; speedup 1.0000x reference)
//
#include <hip/hip_runtime.h>
#include <math.h>

// ClusterGCN 3-layer inference, MI355X — CSR gather + register-blocked dual GEMM.
// R3: 32 nodes/block, 4x4 register tile per thread in GEMM (FMA-dominant inner
// loop), multi-block scan for CSR build.

constexpr int DK = 128;
constexpr int NODES = 32;          // nodes per block in layer kernels
constexpr int CHUNK = 1024;        // scan chunk per block

__global__ void k_hist(const int* __restrict__ col, int* __restrict__ degc, int e) {
    int i = blockIdx.x * blockDim.x + threadIdx.x;
    if (i < e) atomicAdd(&degc[col[i]], 1);
}

// per-chunk sums (256 threads, 1024 elems/block)
__global__ void k_chunksum(const int* __restrict__ degc, int* __restrict__ bsum, int n) {
    int base = blockIdx.x * CHUNK;
    int s = 0;
    for (int t = threadIdx.x; t < CHUNK; t += 256) {
        int i = base + t;
        if (i < n) s += degc[i];
    }
    for (int off = 32; off > 0; off >>= 1) s += __shfl_down(s, off);
    __shared__ int ws[4];
    if ((threadIdx.x & 63) == 0) ws[threadIdx.x >> 6] = s;
    __syncthreads();
    if (threadIdx.x == 0) bsum[blockIdx.x] = ws[0] + ws[1] + ws[2] + ws[3];
}

// exclusive scan of chunk sums (single wave; nb <= 64)
__global__ void k_scansums(int* __restrict__ bsum, int nb) {
    int lane = threadIdx.x;
    int v = (lane < nb) ? bsum[lane] : 0;
    int orig = v;
#pragma unroll
    for (int off = 1; off < 64; off <<= 1) {
        int t = __shfl_up(v, off);
        if (lane >= off) v += t;
    }
    if (lane < nb) bsum[lane] = v - orig;
}

// full scan: offs (exclusive), cursor copy, deginv = 1/(deg+1)
__global__ void k_scanout(const int* __restrict__ degc, const int* __restrict__ bsum,
                          int* __restrict__ offs, int* __restrict__ cursor,
                          float* __restrict__ deginv, int n) {
    const int tid = threadIdx.x;
    const int base = blockIdx.x * CHUNK + tid * 4;
    int v[4];
    int s = 0;
#pragma unroll
    for (int r = 0; r < 4; ++r) {
        int i = base + r;
        v[r] = (i < n) ? degc[i] : 0;
        s += v[r];
    }
    const int lane = tid & 63, wid = tid >> 6;
    int ps = s;
#pragma unroll
    for (int off = 1; off < 64; off <<= 1) {
        int t = __shfl_up(ps, off);
        if (lane >= off) ps += t;
    }
    __shared__ int ws[4];
    if (lane == 63) ws[wid] = ps;
    __syncthreads();
    int wbase = 0;
    for (int w = 0; w < wid; ++w) wbase += ws[w];
    int excl = bsum[blockIdx.x] + wbase + ps - s;
#pragma unroll
    for (int r = 0; r < 4; ++r) {
        int i = base + r;
        if (i < n) {
            offs[i] = excl;
            cursor[i] = excl;
            deginv[i] = 1.0f / (float)(v[r] + 1);
            if (i == n - 1) offs[n] = excl + v[r];
            excl += v[r];
        }
    }
}

__global__ void k_fill(const int* __restrict__ row, const int* __restrict__ col,
                       int* __restrict__ cursor, int* __restrict__ srow, int e) {
    int i = blockIdx.x * blockDim.x + threadIdx.x;
    if (i < e) {
        int c = col[i];
        int pos = atomicAdd(&cursor[c], 1);
        srow[pos] = row[i];
    }
}

// Fused layer: 32 nodes/block, 256 threads.
// Gather: 8 lanes/node, float4; GEMM: 4 rows x 4 cols register tile/thread.
__global__ void k_layer(const float4* __restrict__ xv, const int* __restrict__ offs,
                        const int* __restrict__ srow, const float* __restrict__ deginv,
                        const float* __restrict__ Wout, const float* __restrict__ bvec,
                        const float* __restrict__ Wroot, float* __restrict__ y, int n) {
    constexpr int DOUT = 128;
    __shared__ float sA[NODES][DK];
    __shared__ float sX[NODES][DK];
    const int tid = threadIdx.x;
    const int node0 = blockIdx.x * NODES;
    {
        const int g = tid >> 3;        // node within block
        const int gl = tid & 7;        // lane within node group
        const int node = node0 + g;
        if (node < n) {
            float4 acc[4], self[4];
#pragma unroll
            for (int i = 0; i < 4; ++i) {
                self[i] = xv[(size_t)node * 32 + gl + i * 8];
                acc[i] = self[i];
            }
            const int s = offs[node], e = offs[node + 1];
            for (int p = s; p < e; ++p) {
                int r = srow[p];
#pragma unroll
                for (int i = 0; i < 4; ++i) {
                    float4 v = xv[(size_t)r * 32 + gl + i * 8];
                    acc[i].x += v.x; acc[i].y += v.y; acc[i].z += v.z; acc[i].w += v.w;
                }
            }
            const float w = deginv[node];
#pragma unroll
            for (int i = 0; i < 4; ++i) {
                acc[i].x *= w; acc[i].y *= w; acc[i].z *= w; acc[i].w *= w;
                ((float4*)&sA[g][0])[gl + i * 8] = acc[i];
                ((float4*)&sX[g][0])[gl + i * 8] = self[i];
            }
        }
    }
    __syncthreads();

    const int cg = tid & 31;   // col group: cols j0..j0+3
    const int rg = tid >> 5;   // row group: rows r0..r0+3
    const int j0 = cg * 4;
    const int r0 = rg * 4;
    float acc[4][4];
    const float4 b4 = *(const float4*)&bvec[j0];
#pragma unroll
    for (int r = 0; r < 4; ++r) {
        acc[r][0] = b4.x; acc[r][1] = b4.y; acc[r][2] = b4.z; acc[r][3] = b4.w;
    }

    for (int k = 0; k < DK; k += 4) {
        float4 a[4], xr[4];
#pragma unroll
        for (int r = 0; r < 4; ++r) {
            a[r]  = *(const float4*)&sA[r0 + r][k];
            xr[r] = *(const float4*)&sX[r0 + r][k];
        }
#pragma unroll
        for (int kk = 0; kk < 4; ++kk) {
            const float4 wo = *(const float4*)&Wout[(k + kk) * DOUT + j0];
            const float4 wr = *(const float4*)&Wroot[(k + kk) * DOUT + j0];
#pragma unroll
            for (int r = 0; r < 4; ++r) {
                const float av = ((const float*)&a[r])[kk];
                const float xv2 = ((const float*)&xr[r])[kk];
                acc[r][0] += av * wo.x + xv2 * wr.x;
                acc[r][1] += av * wo.y + xv2 * wr.y;
                acc[r][2] += av * wo.z + xv2 * wr.z;
                acc[r][3] += av * wo.w + xv2 * wr.w;
            }
        }
    }
#pragma unroll
    for (int r = 0; r < 4; ++r) {
        const int node = node0 + r0 + r;
        if (node < n) {
            float4 o;
            o.x = fmaxf(acc[r][0], 0.0f); o.y = fmaxf(acc[r][1], 0.0f);
            o.z = fmaxf(acc[r][2], 0.0f); o.w = fmaxf(acc[r][3], 0.0f);
            *(float4*)&y[(size_t)node * DOUT + j0] = o;
        }
    }
}

// Layer 3: DOUT=64, 32 nodes/block, 2x4 tile/thread, fused relu+log_softmax
// (softmax across the 16 lanes holding one row).
__global__ void k_layer3(const float4* __restrict__ xv, const int* __restrict__ offs,
                         const int* __restrict__ srow, const float* __restrict__ deginv,
                         const float* __restrict__ Wout, const float* __restrict__ bvec,
                         const float* __restrict__ Wroot, float* __restrict__ y, int n) {
    constexpr int DOUT = 64;
    __shared__ float sA[NODES][DK];
    __shared__ float sX[NODES][DK];
    const int tid = threadIdx.x;
    const int node0 = blockIdx.x * NODES;
    {
        const int g = tid >> 3;
        const int gl = tid & 7;
        const int node = node0 + g;
        if (node < n) {
            float4 acc[4], self[4];
#pragma unroll
            for (int i = 0; i < 4; ++i) {
                self[i] = xv[(size_t)node * 32 + gl + i * 8];
                acc[i] = self[i];
            }
            const int s = offs[node], e = offs[node + 1];
            for (int p = s; p < e; ++p) {
                int r = srow[p];
#pragma unroll
                for (int i = 0; i < 4; ++i) {
                    float4 v = xv[(size_t)r * 32 + gl + i * 8];
                    acc[i].x += v.x; acc[i].y += v.y; acc[i].z += v.z; acc[i].w += v.w;
                }
            }
            const float w = deginv[node];
#pragma unroll
            for (int i = 0; i < 4; ++i) {
                acc[i].x *= w; acc[i].y *= w; acc[i].z *= w; acc[i].w *= w;
                ((float4*)&sA[g][0])[gl + i * 8] = acc[i];
                ((float4*)&sX[g][0])[gl + i * 8] = self[i];
            }
        }
    }
    __syncthreads();

    const int cg = tid & 15;   // 16 col groups x 4 cols = 64
    const int rg = tid >> 4;   // 16 row groups x 2 rows = 32
    const int j0 = cg * 4;
    const int r0 = rg * 2;
    float acc[2][4];
    const float4 b4 = *(const float4*)&bvec[j0];
#pragma unroll
    for (int r = 0; r < 2; ++r) {
        acc[r][0] = b4.x; acc[r][1] = b4.y; acc[r][2] = b4.z; acc[r][3] = b4.w;
    }

    for (int k = 0; k < DK; k += 4) {
        float4 a[2], xr[2];
#pragma unroll
        for (int r = 0; r < 2; ++r) {
            a[r]  = *(const float4*)&sA[r0 + r][k];
            xr[r] = *(const float4*)&sX[r0 + r][k];
        }
#pragma unroll
        for (int kk = 0; kk < 4; ++kk) {
            const float4 wo = *(const float4*)&Wout[(k + kk) * DOUT + j0];
            const float4 wr = *(const float4*)&Wroot[(k + kk) * DOUT + j0];
#pragma unroll
            for (int r = 0; r < 2; ++r) {
                const float av = ((const float*)&a[r])[kk];
                const float xv2 = ((const float*)&xr[r])[kk];
                acc[r][0] += av * wo.x + xv2 * wr.x;
                acc[r][1] += av * wo.y + xv2 * wr.y;
                acc[r][2] += av * wo.z + xv2 * wr.z;
                acc[r][3] += av * wo.w + xv2 * wr.w;
            }
        }
    }
#pragma unroll
    for (int r = 0; r < 2; ++r) {
        const int node = node0 + r0 + r;
        float v0 = fmaxf(acc[r][0], 0.0f), v1 = fmaxf(acc[r][1], 0.0f);
        float v2 = fmaxf(acc[r][2], 0.0f), v3 = fmaxf(acc[r][3], 0.0f);
        float m = fmaxf(fmaxf(v0, v1), fmaxf(v2, v3));
#pragma unroll
        for (int off = 1; off < 16; off <<= 1) m = fmaxf(m, __shfl_xor(m, off));
        float s = __expf(v0 - m) + __expf(v1 - m) + __expf(v2 - m) + __expf(v3 - m);
#pragma unroll
        for (int off = 1; off < 16; off <<= 1) s += __shfl_xor(s, off);
        const float lse = m + __logf(s);
        if (node < n) {
            float4 o;
            o.x = v0 - lse; o.y = v1 - lse; o.z = v2 - lse; o.w = v3 - lse;
            *(float4*)&y[(size_t)node * DOUT + j0] = o;
        }
    }
}

extern "C" void kernel_launch(void* const* d_in, const int* in_sizes, int n_in,
                              void* d_out, int out_size, void* d_ws, size_t ws_size,
                              hipStream_t stream) {
    const float* x   = (const float*)d_in[0];
    const int*   ei  = (const int*)d_in[1];
    const float* W1o = (const float*)d_in[2];
    const float* b1  = (const float*)d_in[3];
    const float* W1r = (const float*)d_in[4];
    const float* W2o = (const float*)d_in[5];
    const float* b2  = (const float*)d_in[6];
    const float* W2r = (const float*)d_in[7];
    const float* W3o = (const float*)d_in[8];
    const float* b3  = (const float*)d_in[9];
    const float* W3r = (const float*)d_in[10];

    const int N = in_sizes[0] / DK;   // 50000
    const int E = in_sizes[1] / 2;    // 800000
    const int* row = ei;
    const int* col = ei + E;

    int*   degc   = (int*)d_ws;                        // N (becomes cursor)
    int*   offs   = degc + ((N + 63) & ~63);           // N+1
    float* deginv = (float*)(offs + ((N + 64) & ~63)); // N
    int*   srow   = (int*)(deginv + ((N + 63) & ~63)); // E
    int*   bsum   = srow + ((E + 63) & ~63);           // 64
    float* bufA   = (float*)(bsum + 64);               // N*DK
    float* bufB   = bufA + (size_t)N * DK;             // N*DK
    float* out    = (float*)d_out;

    const int B = 256;
    const int nchunk = (N + CHUNK - 1) / CHUNK;        // 49

    hipMemsetAsync(degc, 0, (size_t)N * sizeof(int), stream);
    k_hist<<<(E + B - 1) / B, B, 0, stream>>>(col, degc, E);
    k_chunksum<<<nchunk, B, 0, stream>>>(degc, bsum, N);
    k_scansums<<<1, 64, 0, stream>>>(bsum, nchunk);
    k_scanout<<<nchunk, B, 0, stream>>>(degc, bsum, offs, degc, deginv, N);
    k_fill<<<(E + B - 1) / B, B, 0, stream>>>(row, col, degc, srow, E);

    const int G = (N + NODES - 1) / NODES;
    k_layer<<<G, 256, 0, stream>>>((const float4*)x,    offs, srow, deginv, W1o, b1, W1r, bufA, N);
    k_layer<<<G, 256, 0, stream>>>((const float4*)bufA, offs, srow, deginv, W2o, b2, W2r, bufB, N);
    k_layer3<<<G, 256, 0, stream>>>((const float4*)bufB, offs, srow, deginv, W3o, b3, W3r, out, N);
}

// Round 4
// 725.027 us; speedup vs baseline: 1.0442x; 1.0442x over previous
//
#include <hip/hip_runtime.h>
#include <math.h>

// ClusterGCN 3-layer inference, MI355X — R4: decoupled gather + dual-GEMM.
// gather: agg = D^-1 (A+I) X   (lean, latency-optimized, no LDS)
// gemm:   Y = relu(agg @ Wout + b + X @ Wroot)  (64-row LDS tile, 8x4/thread)
// layer3: + fused log_softmax over 64 cols (16-lane reduction).

constexpr int DK = 128;
constexpr int CHUNK = 1024;

// ---------------- CSR build ----------------
__global__ void k_hist(const int* __restrict__ col, int* __restrict__ degc, int e) {
    int i = blockIdx.x * blockDim.x + threadIdx.x;
    if (i < e) atomicAdd(&degc[col[i]], 1);
}

__global__ void k_chunksum(const int* __restrict__ degc, int* __restrict__ bsum, int n) {
    int base = blockIdx.x * CHUNK;
    int s = 0;
    for (int t = threadIdx.x; t < CHUNK; t += 256) {
        int i = base + t;
        if (i < n) s += degc[i];
    }
    for (int off = 32; off > 0; off >>= 1) s += __shfl_down(s, off);
    __shared__ int ws[4];
    if ((threadIdx.x & 63) == 0) ws[threadIdx.x >> 6] = s;
    __syncthreads();
    if (threadIdx.x == 0) bsum[blockIdx.x] = ws[0] + ws[1] + ws[2] + ws[3];
}

__global__ void k_scansums(int* __restrict__ bsum, int nb) {
    int lane = threadIdx.x;
    int v = (lane < nb) ? bsum[lane] : 0;
    int orig = v;
#pragma unroll
    for (int off = 1; off < 64; off <<= 1) {
        int t = __shfl_up(v, off);
        if (lane >= off) v += t;
    }
    if (lane < nb) bsum[lane] = v - orig;
}

__global__ void k_scanout(const int* __restrict__ degc, const int* __restrict__ bsum,
                          int* __restrict__ offs, int* __restrict__ cursor,
                          float* __restrict__ deginv, int n) {
    const int tid = threadIdx.x;
    const int base = blockIdx.x * CHUNK + tid * 4;
    int v[4];
    int s = 0;
#pragma unroll
    for (int r = 0; r < 4; ++r) {
        int i = base + r;
        v[r] = (i < n) ? degc[i] : 0;
        s += v[r];
    }
    const int lane = tid & 63, wid = tid >> 6;
    int ps = s;
#pragma unroll
    for (int off = 1; off < 64; off <<= 1) {
        int t = __shfl_up(ps, off);
        if (lane >= off) ps += t;
    }
    __shared__ int ws[4];
    if (lane == 63) ws[wid] = ps;
    __syncthreads();
    int wbase = 0;
    for (int w = 0; w < wid; ++w) wbase += ws[w];
    int excl = bsum[blockIdx.x] + wbase + ps - s;
#pragma unroll
    for (int r = 0; r < 4; ++r) {
        int i = base + r;
        if (i < n) {
            offs[i] = excl;
            cursor[i] = excl;
            deginv[i] = 1.0f / (float)(v[r] + 1);
            if (i == n - 1) offs[n] = excl + v[r];
            excl += v[r];
        }
    }
}

__global__ void k_fill(const int* __restrict__ row, const int* __restrict__ col,
                       int* __restrict__ cursor, int* __restrict__ srow, int e) {
    int i = blockIdx.x * blockDim.x + threadIdx.x;
    if (i < e) {
        int c = col[i];
        int pos = atomicAdd(&cursor[c], 1);
        srow[pos] = row[i];
    }
}

// ---------------- gather: agg = deginv * (x + sum_{r in N} x[r]) ----------------
// 32 lanes per node (one float4/lane = full 128-float row), 8 nodes per block.
__global__ void k_gather(const float4* __restrict__ xv, const int* __restrict__ offs,
                         const int* __restrict__ srow, const float* __restrict__ deginv,
                         float4* __restrict__ agg, int n) {
    const int tid = threadIdx.x;
    const int node = blockIdx.x * 8 + (tid >> 5);
    const int lane = tid & 31;
    if (node >= n) return;
    const size_t rowbase = (size_t)node * 32 + lane;
    float4 acc = xv[rowbase];
    const int s = offs[node], e = offs[node + 1];
    int p = s;
    for (; p + 2 <= e; p += 2) {
        const int r0 = srow[p], r1 = srow[p + 1];
        const float4 v0 = xv[(size_t)r0 * 32 + lane];
        const float4 v1 = xv[(size_t)r1 * 32 + lane];
        acc.x += v0.x + v1.x; acc.y += v0.y + v1.y;
        acc.z += v0.z + v1.z; acc.w += v0.w + v1.w;
    }
    if (p < e) {
        const float4 v = xv[(size_t)srow[p] * 32 + lane];
        acc.x += v.x; acc.y += v.y; acc.z += v.z; acc.w += v.w;
    }
    const float w = deginv[node];
    acc.x *= w; acc.y *= w; acc.z *= w; acc.w *= w;
    agg[rowbase] = acc;
}

// ---------------- dual GEMM: Y = relu(agg@Wout + b + X@Wroot) ----------------
// 64-row tile, 256 threads, thread tile = 8 rows x 4 cols. In-place Y==X safe.
__global__ void k_gemm(const float4* __restrict__ aggv, const float4* __restrict__ xv,
                       const float* __restrict__ Wout, const float* __restrict__ bvec,
                       const float* __restrict__ Wroot, float* __restrict__ y, int n) {
    constexpr int DOUT = 128;
    __shared__ float sA[64][DK];
    __shared__ float sX[64][DK];
    const int tid = threadIdx.x;
    const int row0 = blockIdx.x * 64;
    const int rows_here = min(64, n - row0);

    for (int t = tid; t < 64 * 32; t += 256) {
        const int r = t >> 5, l = t & 31;
        float4 a = make_float4(0.f, 0.f, 0.f, 0.f), x0 = a;
        if (r < rows_here) {
            a  = aggv[(size_t)(row0 + r) * 32 + l];
            x0 = xv[(size_t)(row0 + r) * 32 + l];
        }
        ((float4*)&sA[r][0])[l] = a;
        ((float4*)&sX[r][0])[l] = x0;
    }
    __syncthreads();

    const int cg = tid & 31, rg = tid >> 5;
    const int j0 = cg * 4, r0 = rg * 8;
    float acc[8][4];
    const float4 b4 = *(const float4*)&bvec[j0];
#pragma unroll
    for (int r = 0; r < 8; ++r) {
        acc[r][0] = b4.x; acc[r][1] = b4.y; acc[r][2] = b4.z; acc[r][3] = b4.w;
    }

    for (int k = 0; k < DK; k += 4) {
        float4 a[8], xx[8];
#pragma unroll
        for (int r = 0; r < 8; ++r) {
            a[r]  = *(const float4*)&sA[r0 + r][k];
            xx[r] = *(const float4*)&sX[r0 + r][k];
        }
#pragma unroll
        for (int kk = 0; kk < 4; ++kk) {
            const float4 wo = *(const float4*)&Wout[(k + kk) * DOUT + j0];
            const float4 wr = *(const float4*)&Wroot[(k + kk) * DOUT + j0];
#pragma unroll
            for (int r = 0; r < 8; ++r) {
                const float av = ((const float*)&a[r])[kk];
                const float xr = ((const float*)&xx[r])[kk];
                acc[r][0] += av * wo.x + xr * wr.x;
                acc[r][1] += av * wo.y + xr * wr.y;
                acc[r][2] += av * wo.z + xr * wr.z;
                acc[r][3] += av * wo.w + xr * wr.w;
            }
        }
    }
#pragma unroll
    for (int r = 0; r < 8; ++r) {
        const int node = row0 + r0 + r;
        if (node < n) {
            float4 o;
            o.x = fmaxf(acc[r][0], 0.f); o.y = fmaxf(acc[r][1], 0.f);
            o.z = fmaxf(acc[r][2], 0.f); o.w = fmaxf(acc[r][3], 0.f);
            *(float4*)&y[(size_t)node * DOUT + j0] = o;
        }
    }
}

// ---------------- layer 3 GEMM + relu + log_softmax (DOUT=64) ----------------
// 64-row tile, 256 threads, thread tile = 4 rows x 4 cols; softmax across the
// 16 lanes (cg groups) holding one row.
__global__ void k_gemm3(const float4* __restrict__ aggv, const float4* __restrict__ xv,
                        const float* __restrict__ Wout, const float* __restrict__ bvec,
                        const float* __restrict__ Wroot, float* __restrict__ y, int n) {
    constexpr int DOUT = 64;
    __shared__ float sA[64][DK];
    __shared__ float sX[64][DK];
    const int tid = threadIdx.x;
    const int row0 = blockIdx.x * 64;
    const int rows_here = min(64, n - row0);

    for (int t = tid; t < 64 * 32; t += 256) {
        const int r = t >> 5, l = t & 31;
        float4 a = make_float4(0.f, 0.f, 0.f, 0.f), x0 = a;
        if (r < rows_here) {
            a  = aggv[(size_t)(row0 + r) * 32 + l];
            x0 = xv[(size_t)(row0 + r) * 32 + l];
        }
        ((float4*)&sA[r][0])[l] = a;
        ((float4*)&sX[r][0])[l] = x0;
    }
    __syncthreads();

    const int cg = tid & 15, rg = tid >> 4;
    const int j0 = cg * 4, r0 = rg * 4;
    float acc[4][4];
    const float4 b4 = *(const float4*)&bvec[j0];
#pragma unroll
    for (int r = 0; r < 4; ++r) {
        acc[r][0] = b4.x; acc[r][1] = b4.y; acc[r][2] = b4.z; acc[r][3] = b4.w;
    }

    for (int k = 0; k < DK; k += 4) {
        float4 a[4], xx[4];
#pragma unroll
        for (int r = 0; r < 4; ++r) {
            a[r]  = *(const float4*)&sA[r0 + r][k];
            xx[r] = *(const float4*)&sX[r0 + r][k];
        }
#pragma unroll
        for (int kk = 0; kk < 4; ++kk) {
            const float4 wo = *(const float4*)&Wout[(k + kk) * DOUT + j0];
            const float4 wr = *(const float4*)&Wroot[(k + kk) * DOUT + j0];
#pragma unroll
            for (int r = 0; r < 4; ++r) {
                const float av = ((const float*)&a[r])[kk];
                const float xr = ((const float*)&xx[r])[kk];
                acc[r][0] += av * wo.x + xr * wr.x;
                acc[r][1] += av * wo.y + xr * wr.y;
                acc[r][2] += av * wo.z + xr * wr.z;
                acc[r][3] += av * wo.w + xr * wr.w;
            }
        }
    }
#pragma unroll
    for (int r = 0; r < 4; ++r) {
        const int node = row0 + r0 + r;
        float v0 = fmaxf(acc[r][0], 0.f), v1 = fmaxf(acc[r][1], 0.f);
        float v2 = fmaxf(acc[r][2], 0.f), v3 = fmaxf(acc[r][3], 0.f);
        float m = fmaxf(fmaxf(v0, v1), fmaxf(v2, v3));
#pragma unroll
        for (int off = 1; off < 16; off <<= 1) m = fmaxf(m, __shfl_xor(m, off));
        float s = __expf(v0 - m) + __expf(v1 - m) + __expf(v2 - m) + __expf(v3 - m);
#pragma unroll
        for (int off = 1; off < 16; off <<= 1) s += __shfl_xor(s, off);
        const float lse = m + __logf(s);
        if (node < n) {
            float4 o;
            o.x = v0 - lse; o.y = v1 - lse; o.z = v2 - lse; o.w = v3 - lse;
            *(float4*)&y[(size_t)node * DOUT + j0] = o;
        }
    }
}

extern "C" void kernel_launch(void* const* d_in, const int* in_sizes, int n_in,
                              void* d_out, int out_size, void* d_ws, size_t ws_size,
                              hipStream_t stream) {
    const float* x   = (const float*)d_in[0];
    const int*   ei  = (const int*)d_in[1];
    const float* W1o = (const float*)d_in[2];
    const float* b1  = (const float*)d_in[3];
    const float* W1r = (const float*)d_in[4];
    const float* W2o = (const float*)d_in[5];
    const float* b2  = (const float*)d_in[6];
    const float* W2r = (const float*)d_in[7];
    const float* W3o = (const float*)d_in[8];
    const float* b3  = (const float*)d_in[9];
    const float* W3r = (const float*)d_in[10];

    const int N = in_sizes[0] / DK;   // 50000
    const int E = in_sizes[1] / 2;    // 800000
    const int* row = ei;
    const int* col = ei + E;

    int*   degc   = (int*)d_ws;                        // N (becomes cursor)
    int*   offs   = degc + ((N + 63) & ~63);           // N+1
    float* deginv = (float*)(offs + ((N + 64) & ~63)); // N
    int*   srow   = (int*)(deginv + ((N + 63) & ~63)); // E
    int*   bsum   = srow + ((E + 63) & ~63);           // 64
    float* agg    = (float*)(bsum + 64);               // N*DK
    float* Y1     = agg + (size_t)N * DK;              // N*DK
    float* out    = (float*)d_out;

    const int B = 256;
    const int nchunk = (N + CHUNK - 1) / CHUNK;        // 49

    hipMemsetAsync(degc, 0, (size_t)N * sizeof(int), stream);
    k_hist<<<(E + B - 1) / B, B, 0, stream>>>(col, degc, E);
    k_chunksum<<<nchunk, B, 0, stream>>>(degc, bsum, N);
    k_scansums<<<1, 64, 0, stream>>>(bsum, nchunk);
    k_scanout<<<nchunk, B, 0, stream>>>(degc, bsum, offs, degc, deginv, N);
    k_fill<<<(E + B - 1) / B, B, 0, stream>>>(row, col, degc, srow, E);

    const int Gg = (N + 7) / 8;        // gather grid
    const int Gm = (N + 63) / 64;      // gemm grid

    // layer 1
    k_gather<<<Gg, 256, 0, stream>>>((const float4*)x, offs, srow, deginv, (float4*)agg, N);
    k_gemm<<<Gm, 256, 0, stream>>>((const float4*)agg, (const float4*)x, W1o, b1, W1r, Y1, N);
    // layer 2 (gemm in-place over Y1)
    k_gather<<<Gg, 256, 0, stream>>>((const float4*)Y1, offs, srow, deginv, (float4*)agg, N);
    k_gemm<<<Gm, 256, 0, stream>>>((const float4*)agg, (const float4*)Y1, W2o, b2, W2r, Y1, N);
    // layer 3 + log_softmax
    k_gather<<<Gg, 256, 0, stream>>>((const float4*)Y1, offs, srow, deginv, (float4*)agg, N);
    k_gemm3<<<Gm, 256, 0, stream>>>((const float4*)agg, (const float4*)Y1, W3o, b3, W3r, out, N);
}

// Round 5
// 562.403 us; speedup vs baseline: 1.3461x; 1.2892x over previous
//
#include <hip/hip_runtime.h>
#include <math.h>

// ClusterGCN 3-layer inference, MI355X — R5.
// R4 post-mortem: 64KB LDS/block capped occupancy at 2 blocks/CU (15.7%).
// R5: 32-row GEMM tile (32KB LDS -> 5 blocks/CU, 20 waves), 4x4 thread tile.

constexpr int DK = 128;
constexpr int CHUNK = 1024;

// ---------------- CSR build ----------------
__global__ void k_hist(const int* __restrict__ col, int* __restrict__ degc, int e) {
    int i = blockIdx.x * blockDim.x + threadIdx.x;
    if (i < e) atomicAdd(&degc[col[i]], 1);
}

__global__ void k_chunksum(const int* __restrict__ degc, int* __restrict__ bsum, int n) {
    int base = blockIdx.x * CHUNK;
    int s = 0;
    for (int t = threadIdx.x; t < CHUNK; t += 256) {
        int i = base + t;
        if (i < n) s += degc[i];
    }
    for (int off = 32; off > 0; off >>= 1) s += __shfl_down(s, off);
    __shared__ int ws[4];
    if ((threadIdx.x & 63) == 0) ws[threadIdx.x >> 6] = s;
    __syncthreads();
    if (threadIdx.x == 0) bsum[blockIdx.x] = ws[0] + ws[1] + ws[2] + ws[3];
}

__global__ void k_scansums(int* __restrict__ bsum, int nb) {
    int lane = threadIdx.x;
    int v = (lane < nb) ? bsum[lane] : 0;
    int orig = v;
#pragma unroll
    for (int off = 1; off < 64; off <<= 1) {
        int t = __shfl_up(v, off);
        if (lane >= off) v += t;
    }
    if (lane < nb) bsum[lane] = v - orig;
}

__global__ void k_scanout(const int* __restrict__ degc, const int* __restrict__ bsum,
                          int* __restrict__ offs, int* __restrict__ cursor,
                          float* __restrict__ deginv, int n) {
    const int tid = threadIdx.x;
    const int base = blockIdx.x * CHUNK + tid * 4;
    int v[4];
    int s = 0;
#pragma unroll
    for (int r = 0; r < 4; ++r) {
        int i = base + r;
        v[r] = (i < n) ? degc[i] : 0;
        s += v[r];
    }
    const int lane = tid & 63, wid = tid >> 6;
    int ps = s;
#pragma unroll
    for (int off = 1; off < 64; off <<= 1) {
        int t = __shfl_up(ps, off);
        if (lane >= off) ps += t;
    }
    __shared__ int ws[4];
    if (lane == 63) ws[wid] = ps;
    __syncthreads();
    int wbase = 0;
    for (int w = 0; w < wid; ++w) wbase += ws[w];
    int excl = bsum[blockIdx.x] + wbase + ps - s;
#pragma unroll
    for (int r = 0; r < 4; ++r) {
        int i = base + r;
        if (i < n) {
            offs[i] = excl;
            cursor[i] = excl;
            deginv[i] = 1.0f / (float)(v[r] + 1);
            if (i == n - 1) offs[n] = excl + v[r];
            excl += v[r];
        }
    }
}

__global__ void k_fill(const int* __restrict__ row, const int* __restrict__ col,
                       int* __restrict__ cursor, int* __restrict__ srow, int e) {
    int i = blockIdx.x * blockDim.x + threadIdx.x;
    if (i < e) {
        int c = col[i];
        int pos = atomicAdd(&cursor[c], 1);
        srow[pos] = row[i];
    }
}

// ---------------- gather: agg = deginv * (x + sum_{r in N} x[r]) ----------------
__global__ __launch_bounds__(256, 8)
void k_gather(const float4* __restrict__ xv, const int* __restrict__ offs,
              const int* __restrict__ srow, const float* __restrict__ deginv,
              float4* __restrict__ agg, int n) {
    const int tid = threadIdx.x;
    const int node = blockIdx.x * 8 + (tid >> 5);
    const int lane = tid & 31;
    if (node >= n) return;
    const size_t rowbase = (size_t)node * 32 + lane;
    float4 acc = xv[rowbase];
    const int s = offs[node], e = offs[node + 1];
    int p = s;
    for (; p + 4 <= e; p += 4) {
        const int r0 = srow[p], r1 = srow[p + 1], r2 = srow[p + 2], r3 = srow[p + 3];
        const float4 v0 = xv[(size_t)r0 * 32 + lane];
        const float4 v1 = xv[(size_t)r1 * 32 + lane];
        const float4 v2 = xv[(size_t)r2 * 32 + lane];
        const float4 v3 = xv[(size_t)r3 * 32 + lane];
        acc.x += (v0.x + v1.x) + (v2.x + v3.x);
        acc.y += (v0.y + v1.y) + (v2.y + v3.y);
        acc.z += (v0.z + v1.z) + (v2.z + v3.z);
        acc.w += (v0.w + v1.w) + (v2.w + v3.w);
    }
    for (; p < e; ++p) {
        const float4 v = xv[(size_t)srow[p] * 32 + lane];
        acc.x += v.x; acc.y += v.y; acc.z += v.z; acc.w += v.w;
    }
    const float w = deginv[node];
    acc.x *= w; acc.y *= w; acc.z *= w; acc.w *= w;
    agg[rowbase] = acc;
}

// ---------------- dual GEMM: Y = relu(agg@Wout + b + X@Wroot) ----------------
// 32-row tile (32KB LDS), 256 threads, thread tile = 4 rows x 4 cols.
__global__ __launch_bounds__(256, 5)
void k_gemm(const float4* __restrict__ aggv, const float4* __restrict__ xv,
            const float* __restrict__ Wout, const float* __restrict__ bvec,
            const float* __restrict__ Wroot, float* __restrict__ y, int n) {
    constexpr int DOUT = 128;
    __shared__ float sA[32][DK];
    __shared__ float sX[32][DK];
    const int tid = threadIdx.x;
    const int row0 = blockIdx.x * 32;
    const int rows_here = min(32, n - row0);

    for (int t = tid; t < 32 * 32; t += 256) {
        const int r = t >> 5, l = t & 31;
        float4 a = make_float4(0.f, 0.f, 0.f, 0.f), x0 = a;
        if (r < rows_here) {
            a  = aggv[(size_t)(row0 + r) * 32 + l];
            x0 = xv[(size_t)(row0 + r) * 32 + l];
        }
        ((float4*)&sA[r][0])[l] = a;
        ((float4*)&sX[r][0])[l] = x0;
    }
    __syncthreads();

    const int cg = tid & 31, rg = tid >> 5;
    const int j0 = cg * 4, r0 = rg * 4;
    float acc[4][4];
    const float4 b4 = *(const float4*)&bvec[j0];
#pragma unroll
    for (int r = 0; r < 4; ++r) {
        acc[r][0] = b4.x; acc[r][1] = b4.y; acc[r][2] = b4.z; acc[r][3] = b4.w;
    }

    for (int k = 0; k < DK; k += 4) {
        float4 a[4], xx[4];
#pragma unroll
        for (int r = 0; r < 4; ++r) {
            a[r]  = *(const float4*)&sA[r0 + r][k];
            xx[r] = *(const float4*)&sX[r0 + r][k];
        }
#pragma unroll
        for (int kk = 0; kk < 4; ++kk) {
            const float4 wo = *(const float4*)&Wout[(k + kk) * DOUT + j0];
            const float4 wr = *(const float4*)&Wroot[(k + kk) * DOUT + j0];
#pragma unroll
            for (int r = 0; r < 4; ++r) {
                const float av = ((const float*)&a[r])[kk];
                const float xr = ((const float*)&xx[r])[kk];
                acc[r][0] += av * wo.x + xr * wr.x;
                acc[r][1] += av * wo.y + xr * wr.y;
                acc[r][2] += av * wo.z + xr * wr.z;
                acc[r][3] += av * wo.w + xr * wr.w;
            }
        }
    }
#pragma unroll
    for (int r = 0; r < 4; ++r) {
        const int node = row0 + r0 + r;
        if (node < n) {
            float4 o;
            o.x = fmaxf(acc[r][0], 0.f); o.y = fmaxf(acc[r][1], 0.f);
            o.z = fmaxf(acc[r][2], 0.f); o.w = fmaxf(acc[r][3], 0.f);
            *(float4*)&y[(size_t)node * DOUT + j0] = o;
        }
    }
}

// ---------------- layer 3: GEMM + relu + log_softmax (DOUT=64) ----------------
// 32-row tile, thread tile = 2 rows x 4 cols; softmax across 16 lanes.
__global__ __launch_bounds__(256, 5)
void k_gemm3(const float4* __restrict__ aggv, const float4* __restrict__ xv,
             const float* __restrict__ Wout, const float* __restrict__ bvec,
             const float* __restrict__ Wroot, float* __restrict__ y, int n) {
    constexpr int DOUT = 64;
    __shared__ float sA[32][DK];
    __shared__ float sX[32][DK];
    const int tid = threadIdx.x;
    const int row0 = blockIdx.x * 32;
    const int rows_here = min(32, n - row0);

    for (int t = tid; t < 32 * 32; t += 256) {
        const int r = t >> 5, l = t & 31;
        float4 a = make_float4(0.f, 0.f, 0.f, 0.f), x0 = a;
        if (r < rows_here) {
            a  = aggv[(size_t)(row0 + r) * 32 + l];
            x0 = xv[(size_t)(row0 + r) * 32 + l];
        }
        ((float4*)&sA[r][0])[l] = a;
        ((float4*)&sX[r][0])[l] = x0;
    }
    __syncthreads();

    const int cg = tid & 15, rg = tid >> 4;
    const int j0 = cg * 4, r0 = rg * 2;
    float acc[2][4];
    const float4 b4 = *(const float4*)&bvec[j0];
#pragma unroll
    for (int r = 0; r < 2; ++r) {
        acc[r][0] = b4.x; acc[r][1] = b4.y; acc[r][2] = b4.z; acc[r][3] = b4.w;
    }

    for (int k = 0; k < DK; k += 4) {
        float4 a[2], xx[2];
#pragma unroll
        for (int r = 0; r < 2; ++r) {
            a[r]  = *(const float4*)&sA[r0 + r][k];
            xx[r] = *(const float4*)&sX[r0 + r][k];
        }
#pragma unroll
        for (int kk = 0; kk < 4; ++kk) {
            const float4 wo = *(const float4*)&Wout[(k + kk) * DOUT + j0];
            const float4 wr = *(const float4*)&Wroot[(k + kk) * DOUT + j0];
#pragma unroll
            for (int r = 0; r < 2; ++r) {
                const float av = ((const float*)&a[r])[kk];
                const float xr = ((const float*)&xx[r])[kk];
                acc[r][0] += av * wo.x + xr * wr.x;
                acc[r][1] += av * wo.y + xr * wr.y;
                acc[r][2] += av * wo.z + xr * wr.z;
                acc[r][3] += av * wo.w + xr * wr.w;
            }
        }
    }
#pragma unroll
    for (int r = 0; r < 2; ++r) {
        const int node = row0 + r0 + r;
        float v0 = fmaxf(acc[r][0], 0.f), v1 = fmaxf(acc[r][1], 0.f);
        float v2 = fmaxf(acc[r][2], 0.f), v3 = fmaxf(acc[r][3], 0.f);
        float m = fmaxf(fmaxf(v0, v1), fmaxf(v2, v3));
#pragma unroll
        for (int off = 1; off < 16; off <<= 1) m = fmaxf(m, __shfl_xor(m, off));
        float s = __expf(v0 - m) + __expf(v1 - m) + __expf(v2 - m) + __expf(v3 - m);
#pragma unroll
        for (int off = 1; off < 16; off <<= 1) s += __shfl_xor(s, off);
        const float lse = m + __logf(s);
        if (node < n) {
            float4 o;
            o.x = v0 - lse; o.y = v1 - lse; o.z = v2 - lse; o.w = v3 - lse;
            *(float4*)&y[(size_t)node * DOUT + j0] = o;
        }
    }
}

extern "C" void kernel_launch(void* const* d_in, const int* in_sizes, int n_in,
                              void* d_out, int out_size, void* d_ws, size_t ws_size,
                              hipStream_t stream) {
    const float* x   = (const float*)d_in[0];
    const int*   ei  = (const int*)d_in[1];
    const float* W1o = (const float*)d_in[2];
    const float* b1  = (const float*)d_in[3];
    const float* W1r = (const float*)d_in[4];
    const float* W2o = (const float*)d_in[5];
    const float* b2  = (const float*)d_in[6];
    const float* W2r = (const float*)d_in[7];
    const float* W3o = (const float*)d_in[8];
    const float* b3  = (const float*)d_in[9];
    const float* W3r = (const float*)d_in[10];

    const int N = in_sizes[0] / DK;   // 50000
    const int E = in_sizes[1] / 2;    // 800000
    const int* row = ei;
    const int* col = ei + E;

    int*   degc   = (int*)d_ws;                        // N (becomes cursor)
    int*   offs   = degc + ((N + 63) & ~63);           // N+1
    float* deginv = (float*)(offs + ((N + 64) & ~63)); // N
    int*   srow   = (int*)(deginv + ((N + 63) & ~63)); // E
    int*   bsum   = srow + ((E + 63) & ~63);           // 64
    float* agg    = (float*)(bsum + 64);               // N*DK
    float* Y1     = agg + (size_t)N * DK;              // N*DK
    float* out    = (float*)d_out;

    const int B = 256;
    const int nchunk = (N + CHUNK - 1) / CHUNK;        // 49

    hipMemsetAsync(degc, 0, (size_t)N * sizeof(int), stream);
    k_hist<<<(E + B - 1) / B, B, 0, stream>>>(col, degc, E);
    k_chunksum<<<nchunk, B, 0, stream>>>(degc, bsum, N);
    k_scansums<<<1, 64, 0, stream>>>(bsum, nchunk);
    k_scanout<<<nchunk, B, 0, stream>>>(degc, bsum, offs, degc, deginv, N);
    k_fill<<<(E + B - 1) / B, B, 0, stream>>>(row, col, degc, srow, E);

    const int Gg = (N + 7) / 8;        // gather grid
    const int Gm = (N + 31) / 32;      // gemm grid

    // layer 1
    k_gather<<<Gg, 256, 0, stream>>>((const float4*)x, offs, srow, deginv, (float4*)agg, N);
    k_gemm<<<Gm, 256, 0, stream>>>((const float4*)agg, (const float4*)x, W1o, b1, W1r, Y1, N);
    // layer 2 (gemm in-place over Y1)
    k_gather<<<Gg, 256, 0, stream>>>((const float4*)Y1, offs, srow, deginv, (float4*)agg, N);
    k_gemm<<<Gm, 256, 0, stream>>>((const float4*)agg, (const float4*)Y1, W2o, b2, W2r, Y1, N);
    // layer 3 + log_softmax
    k_gather<<<Gg, 256, 0, stream>>>((const float4*)Y1, offs, srow, deginv, (float4*)agg, N);
    k_gemm3<<<Gm, 256, 0, stream>>>((const float4*)agg, (const float4*)Y1, W3o, b3, W3r, out, N);
}

// Round 6
// 354.848 us; speedup vs baseline: 2.1335x; 1.5849x over previous
//
#include <hip/hip_runtime.h>
#include <math.h>

// ClusterGCN 3-layer inference, MI355X — R6: bf16 activations + MFMA GEMM.
// Dual GEMM folded to single K=256 GEMM: Y = relu([agg|X] @ [Wout;Wroot] + b).
// mfma_f32_16x16x32_bf16; A-frags direct from global; B-frags in registers
// (weights pre-swizzled to fragment layout). Gather in bf16 w/ fp32 accum.

constexpr int DK = 128;
constexpr int CHUNK = 1024;

typedef __attribute__((ext_vector_type(8))) short bf16x8;
typedef __attribute__((ext_vector_type(4))) float f32x4;

__device__ inline unsigned short f2bf(float f) {
    unsigned int u; __builtin_memcpy(&u, &f, 4);
    unsigned int r = (u + 0x7FFFu + ((u >> 16) & 1u)) >> 16;
    return (unsigned short)r;
}
__device__ inline float blo(unsigned int u) {
    unsigned int t = u << 16; float f; __builtin_memcpy(&f, &t, 4); return f;
}
__device__ inline float bhi(unsigned int u) {
    unsigned int t = u & 0xffff0000u; float f; __builtin_memcpy(&f, &t, 4); return f;
}

// ---------------- CSR build (unchanged from R5) ----------------
__global__ void k_hist(const int* __restrict__ col, int* __restrict__ degc, int e) {
    int i = blockIdx.x * blockDim.x + threadIdx.x;
    if (i < e) atomicAdd(&degc[col[i]], 1);
}

__global__ void k_chunksum(const int* __restrict__ degc, int* __restrict__ bsum, int n) {
    int base = blockIdx.x * CHUNK;
    int s = 0;
    for (int t = threadIdx.x; t < CHUNK; t += 256) {
        int i = base + t;
        if (i < n) s += degc[i];
    }
    for (int off = 32; off > 0; off >>= 1) s += __shfl_down(s, off);
    __shared__ int ws[4];
    if ((threadIdx.x & 63) == 0) ws[threadIdx.x >> 6] = s;
    __syncthreads();
    if (threadIdx.x == 0) bsum[blockIdx.x] = ws[0] + ws[1] + ws[2] + ws[3];
}

__global__ void k_scansums(int* __restrict__ bsum, int nb) {
    int lane = threadIdx.x;
    int v = (lane < nb) ? bsum[lane] : 0;
    int orig = v;
#pragma unroll
    for (int off = 1; off < 64; off <<= 1) {
        int t = __shfl_up(v, off);
        if (lane >= off) v += t;
    }
    if (lane < nb) bsum[lane] = v - orig;
}

__global__ void k_scanout(const int* __restrict__ degc, const int* __restrict__ bsum,
                          int* __restrict__ offs, int* __restrict__ cursor,
                          float* __restrict__ deginv, int n) {
    const int tid = threadIdx.x;
    const int base = blockIdx.x * CHUNK + tid * 4;
    int v[4];
    int s = 0;
#pragma unroll
    for (int r = 0; r < 4; ++r) {
        int i = base + r;
        v[r] = (i < n) ? degc[i] : 0;
        s += v[r];
    }
    const int lane = tid & 63, wid = tid >> 6;
    int ps = s;
#pragma unroll
    for (int off = 1; off < 64; off <<= 1) {
        int t = __shfl_up(ps, off);
        if (lane >= off) ps += t;
    }
    __shared__ int ws[4];
    if (lane == 63) ws[wid] = ps;
    __syncthreads();
    int wbase = 0;
    for (int w = 0; w < wid; ++w) wbase += ws[w];
    int excl = bsum[blockIdx.x] + wbase + ps - s;
#pragma unroll
    for (int r = 0; r < 4; ++r) {
        int i = base + r;
        if (i < n) {
            offs[i] = excl;
            cursor[i] = excl;
            deginv[i] = 1.0f / (float)(v[r] + 1);
            if (i == n - 1) offs[n] = excl + v[r];
            excl += v[r];
        }
    }
}

__global__ void k_fill(const int* __restrict__ row, const int* __restrict__ col,
                       int* __restrict__ cursor, int* __restrict__ srow, int e) {
    int i = blockIdx.x * blockDim.x + threadIdx.x;
    if (i < e) {
        int c = col[i];
        int pos = atomicAdd(&cursor[c], 1);
        srow[pos] = row[i];
    }
}

// ---------------- fp32 -> bf16 convert (x) ----------------
__global__ void k_cvtx(const float4* __restrict__ x, uint2* __restrict__ xb, int n4) {
    int i = blockIdx.x * 256 + threadIdx.x;
    if (i >= n4) return;
    float4 v = x[i];
    uint2 o;
    o.x = (unsigned)f2bf(v.x) | ((unsigned)f2bf(v.y) << 16);
    o.y = (unsigned)f2bf(v.z) | ((unsigned)f2bf(v.w) << 16);
    xb[i] = o;
}

// ---------------- weight prep: swizzle [Wout;Wroot] into B-frag layout ------
// frag(t,u) lane L element j = W[k=t*32+(L>>4)*8+j][n=u*16+(L&15)],
// k<128 -> Wout, else Wroot. Stored as uint4 (8 bf16) at [((t*(dout/16)+u)*64+L)].
__global__ void k_wprep(const float* __restrict__ Wout, const float* __restrict__ Wroot,
                        uint4* __restrict__ frag, int dout) {
    int tid = blockIdx.x * 256 + threadIdx.x;
    int total = 8 * (dout >> 4) * 64;
    if (tid >= total) return;
    int L = tid & 63;
    int fu = (tid >> 6) % (dout >> 4);
    int t = (tid >> 6) / (dout >> 4);
    int quad = L >> 4, l15 = L & 15;
    int n = fu * 16 + l15;
    unsigned int p[4];
#pragma unroll
    for (int jj = 0; jj < 4; ++jj) {
        int k0 = t * 32 + quad * 8 + jj * 2;
        float v0 = (k0 < 128) ? Wout[k0 * dout + n] : Wroot[(k0 - 128) * dout + n];
        int k1 = k0 + 1;
        float v1 = (k1 < 128) ? Wout[k1 * dout + n] : Wroot[(k1 - 128) * dout + n];
        p[jj] = (unsigned)f2bf(v0) | ((unsigned)f2bf(v1) << 16);
    }
    frag[tid] = make_uint4(p[0], p[1], p[2], p[3]);
}

// ---------------- gather (bf16 in/out, fp32 accum) ----------------
// 32 lanes/node (uint2 = 4 bf16 per lane), 8 nodes/block.
__global__ __launch_bounds__(256, 8)
void k_gather_bf(const uint2* __restrict__ xb, const int* __restrict__ offs,
                 const int* __restrict__ srow, const float* __restrict__ deginv,
                 uint2* __restrict__ aggb, int n) {
    const int node = blockIdx.x * 8 + (threadIdx.x >> 5);
    const int lane = threadIdx.x & 31;
    if (node >= n) return;
    const size_t rb = (size_t)node * 32 + lane;   // row = 32 uint2
    uint2 sv = xb[rb];
    float a0 = blo(sv.x), a1 = bhi(sv.x), a2 = blo(sv.y), a3 = bhi(sv.y);
    const int s = offs[node], e = offs[node + 1];
    int p = s;
    for (; p + 4 <= e; p += 4) {
        const int r0 = srow[p], r1 = srow[p + 1], r2 = srow[p + 2], r3 = srow[p + 3];
        const uint2 v0 = xb[(size_t)r0 * 32 + lane];
        const uint2 v1 = xb[(size_t)r1 * 32 + lane];
        const uint2 v2 = xb[(size_t)r2 * 32 + lane];
        const uint2 v3 = xb[(size_t)r3 * 32 + lane];
        a0 += (blo(v0.x) + blo(v1.x)) + (blo(v2.x) + blo(v3.x));
        a1 += (bhi(v0.x) + bhi(v1.x)) + (bhi(v2.x) + bhi(v3.x));
        a2 += (blo(v0.y) + blo(v1.y)) + (blo(v2.y) + blo(v3.y));
        a3 += (bhi(v0.y) + bhi(v1.y)) + (bhi(v2.y) + bhi(v3.y));
    }
    for (; p < e; ++p) {
        const uint2 v = xb[(size_t)srow[p] * 32 + lane];
        a0 += blo(v.x); a1 += bhi(v.x); a2 += blo(v.y); a3 += bhi(v.y);
    }
    const float w = deginv[node];
    uint2 o;
    o.x = (unsigned)f2bf(a0 * w) | ((unsigned)f2bf(a1 * w) << 16);
    o.y = (unsigned)f2bf(a2 * w) | ((unsigned)f2bf(a3 * w) << 16);
    aggb[rb] = o;
}

// ---------------- MFMA GEMM (layers 1,2): Y = relu([agg|X]@[Wo;Wr]+b) -------
// Block = 4 waves, M-tile = 64 rows. Wave w owns cols [w*32, w*32+32).
// K=256: t=0..3 from aggb, t=4..7 from xb. B-frags in regs, A-frags from global.
__global__ __launch_bounds__(256, 2)
void k_gemm_mfma(const unsigned short* __restrict__ aggb,
                 const unsigned short* __restrict__ xb,
                 const uint4* __restrict__ wfrag, const float* __restrict__ bvec,
                 unsigned short* __restrict__ y, int n) {
    const int tid = threadIdx.x;
    const int w = tid >> 6, L = tid & 63;
    const int quad = L >> 4, l15 = L & 15;
    const int m0 = blockIdx.x * 64;

    bf16x8 bfr[8][2];
#pragma unroll
    for (int t = 0; t < 8; ++t)
#pragma unroll
        for (int u = 0; u < 2; ++u)
            bfr[t][u] = *(const bf16x8*)&wfrag[(size_t)((t * 8 + (w * 2 + u)) * 64 + L)];

    f32x4 acc[4][2];
#pragma unroll
    for (int mt = 0; mt < 4; ++mt)
#pragma unroll
        for (int u = 0; u < 2; ++u)
            acc[mt][u] = (f32x4){0.f, 0.f, 0.f, 0.f};

    const bf16x8 zf = {0, 0, 0, 0, 0, 0, 0, 0};
#pragma unroll
    for (int t = 0; t < 8; ++t) {
        const unsigned short* Ab = (t < 4) ? aggb : xb;
        const int koff = (t & 3) * 32 + quad * 8;
        bf16x8 af[4];
#pragma unroll
        for (int mt = 0; mt < 4; ++mt) {
            const int r = m0 + mt * 16 + l15;
            af[mt] = (r < n) ? *(const bf16x8*)(Ab + (size_t)r * 128 + koff) : zf;
        }
#pragma unroll
        for (int mt = 0; mt < 4; ++mt)
#pragma unroll
            for (int u = 0; u < 2; ++u)
                acc[mt][u] = __builtin_amdgcn_mfma_f32_16x16x32_bf16(
                    af[mt], bfr[t][u], acc[mt][u], 0, 0, 0);
    }

    float bb[2];
    bb[0] = bvec[w * 32 + l15];
    bb[1] = bvec[w * 32 + 16 + l15];
#pragma unroll
    for (int mt = 0; mt < 4; ++mt)
#pragma unroll
        for (int u = 0; u < 2; ++u)
#pragma unroll
            for (int r4 = 0; r4 < 4; ++r4) {
                const int r = m0 + mt * 16 + quad * 4 + r4;
                if (r < n) {
                    float v = fmaxf(acc[mt][u][r4] + bb[u], 0.f);
                    y[(size_t)r * 128 + w * 32 + u * 16 + l15] = f2bf(v);
                }
            }
}

// ---------------- layer 3: MFMA GEMM (DOUT=64) + relu + log_softmax ---------
// Block = 4 waves, M-tile = 128 rows. Wave w: rows (w>>1)*64.., cols (w&1)*32..
__global__ __launch_bounds__(256, 2)
void k_gemm3_mfma(const unsigned short* __restrict__ aggb,
                  const unsigned short* __restrict__ xb,
                  const uint4* __restrict__ wfrag, const float* __restrict__ bvec,
                  float* __restrict__ out, int n) {
    const int tid = threadIdx.x;
    const int w = tid >> 6, L = tid & 63;
    const int quad = L >> 4, l15 = L & 15;
    const int whalf = w & 1;
    const int m0 = blockIdx.x * 128 + (w >> 1) * 64;

    bf16x8 bfr[8][2];
#pragma unroll
    for (int t = 0; t < 8; ++t)
#pragma unroll
        for (int u = 0; u < 2; ++u)
            bfr[t][u] = *(const bf16x8*)&wfrag[(size_t)((t * 4 + (whalf * 2 + u)) * 64 + L)];

    f32x4 acc[4][2];
#pragma unroll
    for (int mt = 0; mt < 4; ++mt)
#pragma unroll
        for (int u = 0; u < 2; ++u)
            acc[mt][u] = (f32x4){0.f, 0.f, 0.f, 0.f};

    const bf16x8 zf = {0, 0, 0, 0, 0, 0, 0, 0};
#pragma unroll
    for (int t = 0; t < 8; ++t) {
        const unsigned short* Ab = (t < 4) ? aggb : xb;
        const int koff = (t & 3) * 32 + quad * 8;
        bf16x8 af[4];
#pragma unroll
        for (int mt = 0; mt < 4; ++mt) {
            const int r = m0 + mt * 16 + l15;
            af[mt] = (r < n) ? *(const bf16x8*)(Ab + (size_t)r * 128 + koff) : zf;
        }
#pragma unroll
        for (int mt = 0; mt < 4; ++mt)
#pragma unroll
            for (int u = 0; u < 2; ++u)
                acc[mt][u] = __builtin_amdgcn_mfma_f32_16x16x32_bf16(
                    af[mt], bfr[t][u], acc[mt][u], 0, 0, 0);
    }

    float bb[2];
    bb[0] = bvec[whalf * 32 + l15];
    bb[1] = bvec[whalf * 32 + 16 + l15];
#pragma unroll
    for (int mt = 0; mt < 4; ++mt)
#pragma unroll
        for (int u = 0; u < 2; ++u)
#pragma unroll
            for (int r4 = 0; r4 < 4; ++r4)
                acc[mt][u][r4] = fmaxf(acc[mt][u][r4] + bb[u], 0.f);

    __shared__ float pm[128][2];
    __shared__ float ps[128][2];
    const int rlb = (w >> 1) * 64;

    // Phase A: per-row partial max over this wave's 32 cols.
#pragma unroll
    for (int mt = 0; mt < 4; ++mt)
#pragma unroll
        for (int r4 = 0; r4 < 4; ++r4) {
            float p = fmaxf(acc[mt][0][r4], acc[mt][1][r4]);
            p = fmaxf(p, __shfl_xor(p, 1));
            p = fmaxf(p, __shfl_xor(p, 2));
            p = fmaxf(p, __shfl_xor(p, 4));
            p = fmaxf(p, __shfl_xor(p, 8));
            if (l15 == 0) pm[rlb + mt * 16 + quad * 4 + r4][whalf] = p;
        }
    __syncthreads();

    // Phase B: partial exp-sums with global row max.
#pragma unroll
    for (int mt = 0; mt < 4; ++mt)
#pragma unroll
        for (int r4 = 0; r4 < 4; ++r4) {
            const int rl = rlb + mt * 16 + quad * 4 + r4;
            const float M = fmaxf(pm[rl][0], pm[rl][1]);
            float s = __expf(acc[mt][0][r4] - M) + __expf(acc[mt][1][r4] - M);
            s += __shfl_xor(s, 1);
            s += __shfl_xor(s, 2);
            s += __shfl_xor(s, 4);
            s += __shfl_xor(s, 8);
            if (l15 == 0) ps[rl][whalf] = s;
        }
    __syncthreads();

    // Phase C: write out.
#pragma unroll
    for (int mt = 0; mt < 4; ++mt)
#pragma unroll
        for (int r4 = 0; r4 < 4; ++r4) {
            const int rl = rlb + mt * 16 + quad * 4 + r4;
            const int r = blockIdx.x * 128 + rl;
            const float M = fmaxf(pm[rl][0], pm[rl][1]);
            const float lse = M + __logf(ps[rl][0] + ps[rl][1]);
            if (r < n) {
#pragma unroll
                for (int u = 0; u < 2; ++u)
                    out[(size_t)r * 64 + whalf * 32 + u * 16 + l15] =
                        acc[mt][u][r4] - lse;
            }
        }
}

extern "C" void kernel_launch(void* const* d_in, const int* in_sizes, int n_in,
                              void* d_out, int out_size, void* d_ws, size_t ws_size,
                              hipStream_t stream) {
    const float* x   = (const float*)d_in[0];
    const int*   ei  = (const int*)d_in[1];
    const float* W1o = (const float*)d_in[2];
    const float* b1  = (const float*)d_in[3];
    const float* W1r = (const float*)d_in[4];
    const float* W2o = (const float*)d_in[5];
    const float* b2  = (const float*)d_in[6];
    const float* W2r = (const float*)d_in[7];
    const float* W3o = (const float*)d_in[8];
    const float* b3  = (const float*)d_in[9];
    const float* W3r = (const float*)d_in[10];

    const int N = in_sizes[0] / DK;   // 50000
    const int E = in_sizes[1] / 2;    // 800000
    const int* row = ei;
    const int* col = ei + E;

    // workspace (4-byte units)
    int*   degc   = (int*)d_ws;                         // N (becomes cursor)
    int*   offs   = degc + ((N + 63) & ~63);            // N+1
    float* deginv = (float*)(offs + ((N + 64) & ~63));  // N
    int*   srow   = (int*)(deginv + ((N + 63) & ~63));  // E
    int*   bsum   = srow + ((E + 63) & ~63);            // 64
    uint4* wf1    = (uint4*)(bsum + 64);                // 4096 uint4
    uint4* wf2    = wf1 + 4096;                         // 4096 uint4
    uint4* wf3    = wf2 + 4096;                         // 2048 uint4
    unsigned short* xbuf = (unsigned short*)(wf3 + 2048);   // N*128 bf16
    unsigned short* aggb = xbuf + (size_t)N * 128;          // N*128 bf16
    unsigned short* Ya   = aggb + (size_t)N * 128;          // N*128 bf16
    float* out = (float*)d_out;

    const int B = 256;
    const int nchunk = (N + CHUNK - 1) / CHUNK;

    // prep: x->bf16, weights->frag layout
    const int n4 = N * 32;  // float4 count
    k_cvtx<<<(n4 + 255) / 256, 256, 0, stream>>>((const float4*)x, (uint2*)xbuf, n4);
    k_wprep<<<16, 256, 0, stream>>>(W1o, W1r, wf1, 128);
    k_wprep<<<16, 256, 0, stream>>>(W2o, W2r, wf2, 128);
    k_wprep<<<8, 256, 0, stream>>>(W3o, W3r, wf3, 64);

    // CSR build
    hipMemsetAsync(degc, 0, (size_t)N * sizeof(int), stream);
    k_hist<<<(E + B - 1) / B, B, 0, stream>>>(col, degc, E);
    k_chunksum<<<nchunk, B, 0, stream>>>(degc, bsum, N);
    k_scansums<<<1, 64, 0, stream>>>(bsum, nchunk);
    k_scanout<<<nchunk, B, 0, stream>>>(degc, bsum, offs, degc, deginv, N);
    k_fill<<<(E + B - 1) / B, B, 0, stream>>>(row, col, degc, srow, E);

    const int Gg = (N + 7) / 8;
    const int Gm = (N + 63) / 64;
    const int G3 = (N + 127) / 128;

    // layer 1: xbuf -> aggb -> Ya
    k_gather_bf<<<Gg, 256, 0, stream>>>((const uint2*)xbuf, offs, srow, deginv, (uint2*)aggb, N);
    k_gemm_mfma<<<Gm, 256, 0, stream>>>(aggb, xbuf, wf1, b1, Ya, N);
    // layer 2: Ya -> aggb -> xbuf (xbuf free after layer 1)
    k_gather_bf<<<Gg, 256, 0, stream>>>((const uint2*)Ya, offs, srow, deginv, (uint2*)aggb, N);
    k_gemm_mfma<<<Gm, 256, 0, stream>>>(aggb, Ya, wf2, b2, xbuf, N);
    // layer 3: xbuf -> aggb -> out (fp32 + log_softmax)
    k_gather_bf<<<Gg, 256, 0, stream>>>((const uint2*)xbuf, offs, srow, deginv, (uint2*)aggb, N);
    k_gemm3_mfma<<<G3, 256, 0, stream>>>(aggb, xbuf, wf3, b3, out, N);
}

// Round 7
// 295.040 us; speedup vs baseline: 2.5660x; 1.2027x over previous
//
#include <hip/hip_runtime.h>
#include <math.h>

// ClusterGCN 3-layer inference, MI355X — R7.
// R6 post-mortem: legacy CSR build (random 4B scatter in k_fill -> 52MB of
// 64B-line HBM writes) cost ~80us. R7 replaces it with a two-level counting
// sort: 256 col-buckets, LDS-staged partition (dense writes), then per-bucket
// fill with LDS cursors (writes confined to a 12.5KB window). Layers (bf16
// gather + MFMA GEMM) unchanged from R6.

constexpr int DK = 128;
constexpr int NBUCK = 256;

typedef __attribute__((ext_vector_type(8))) short bf16x8;
typedef __attribute__((ext_vector_type(4))) float f32x4;

__device__ inline unsigned short f2bf(float f) {
    unsigned int u; __builtin_memcpy(&u, &f, 4);
    unsigned int r = (u + 0x7FFFu + ((u >> 16) & 1u)) >> 16;
    return (unsigned short)r;
}
__device__ inline float blo(unsigned int u) {
    unsigned int t = u << 16; float f; __builtin_memcpy(&f, &t, 4); return f;
}
__device__ inline float bhi(unsigned int u) {
    unsigned int t = u & 0xffff0000u; float f; __builtin_memcpy(&f, &t, 4); return f;
}

// ---------------- fp32 -> bf16 convert (x); block 0 also zeroes bhist -------
__global__ void k_cvtx(const float4* __restrict__ x, uint2* __restrict__ xb,
                       int* __restrict__ bhist, int n4) {
    if (blockIdx.x == 0) bhist[threadIdx.x] = 0;   // consumed by k_bhist (later launch)
    int i = blockIdx.x * 256 + threadIdx.x;
    if (i >= n4) return;
    float4 v = x[i];
    uint2 o;
    o.x = (unsigned)f2bf(v.x) | ((unsigned)f2bf(v.y) << 16);
    o.y = (unsigned)f2bf(v.z) | ((unsigned)f2bf(v.w) << 16);
    xb[i] = o;
}

// ---------------- weight prep: swizzle [Wout;Wroot] into B-frag layout ------
__global__ void k_wprep(const float* __restrict__ Wout, const float* __restrict__ Wroot,
                        uint4* __restrict__ frag, int dout) {
    int tid = blockIdx.x * 256 + threadIdx.x;
    int total = 8 * (dout >> 4) * 64;
    if (tid >= total) return;
    int L = tid & 63;
    int fu = (tid >> 6) % (dout >> 4);
    int t = (tid >> 6) / (dout >> 4);
    int quad = L >> 4, l15 = L & 15;
    int n = fu * 16 + l15;
    unsigned int p[4];
#pragma unroll
    for (int jj = 0; jj < 4; ++jj) {
        int k0 = t * 32 + quad * 8 + jj * 2;
        float v0 = (k0 < 128) ? Wout[k0 * dout + n] : Wroot[(k0 - 128) * dout + n];
        int k1 = k0 + 1;
        float v1 = (k1 < 128) ? Wout[k1 * dout + n] : Wroot[(k1 - 128) * dout + n];
        p[jj] = (unsigned)f2bf(v0) | ((unsigned)f2bf(v1) << 16);
    }
    frag[tid] = make_uint4(p[0], p[1], p[2], p[3]);
}

// ---------------- CSR build: two-level counting sort ----------------
// 1) bucket histogram (LDS-staged)
__global__ void k_bhist(const int* __restrict__ col, int* __restrict__ bhist,
                        int e, int bspan) {
    __shared__ int h[NBUCK];
    h[threadIdx.x] = 0;
    __syncthreads();
    for (int i = blockIdx.x * blockDim.x + threadIdx.x; i < e;
         i += gridDim.x * blockDim.x)
        atomicAdd(&h[col[i] / bspan], 1);
    __syncthreads();
    int v = h[threadIdx.x];
    if (v) atomicAdd(&bhist[threadIdx.x], v);
}

// 2) scan 256 bucket counts -> boffs[0..256] (=CSR segment bases), cursors
__global__ void k_bscan(const int* __restrict__ bhist, int* __restrict__ boffs,
                        int* __restrict__ bcur, int* __restrict__ offs,
                        int n, int e) {
    __shared__ int wsum[4];
    const int tid = threadIdx.x, lane = tid & 63, wid = tid >> 6;
    int v = bhist[tid];
    int ps = v;
#pragma unroll
    for (int off = 1; off < 64; off <<= 1) {
        int t = __shfl_up(ps, off);
        if (lane >= off) ps += t;
    }
    if (lane == 63) wsum[wid] = ps;
    __syncthreads();
    int wb = 0;
    for (int w = 0; w < wid; ++w) wb += wsum[w];
    int excl = wb + ps - v;
    boffs[tid] = excl;
    bcur[tid] = excl;
    if (tid == 255) boffs[256] = excl + v;   // == e
    if (tid == 0) offs[n] = e;
}

// 3) partition edges into buckets; packed (colofs<<16)|row (row<65536, ofs<256)
__global__ void k_part(const int* __restrict__ row, const int* __restrict__ col,
                       int* __restrict__ bcur, unsigned int* __restrict__ ebuf,
                       int e, int bspan) {
    __shared__ int cnt[NBUCK];
    __shared__ int base[NBUCK];
    const int tid = threadIdx.x;
    const int t0 = blockIdx.x * 4096;
    cnt[tid] = 0;
    __syncthreads();
    int bk[16];
#pragma unroll
    for (int k = 0; k < 16; ++k) {
        int i = t0 + k * 256 + tid;
        int b = -1;
        if (i < e) { b = col[i] / bspan; atomicAdd(&cnt[b], 1); }
        bk[k] = b;
    }
    __syncthreads();
    base[tid] = cnt[tid] ? atomicAdd(&bcur[tid], cnt[tid]) : 0;
    cnt[tid] = 0;
    __syncthreads();
#pragma unroll
    for (int k = 0; k < 16; ++k) {
        int i = t0 + k * 256 + tid;
        if (i < e) {
            int b = bk[k];
            int slot = base[b] + atomicAdd(&cnt[b], 1);
            unsigned int colofs = (unsigned)(col[i] - b * bspan);
            ebuf[slot] = ((unsigned)row[i] & 0xFFFFu) | (colofs << 16);
        }
    }
}

// 4) per-bucket fill: LDS per-col counts -> scan -> offs/deginv + srow scatter
__global__ void k_fillb(const unsigned int* __restrict__ ebuf,
                        const int* __restrict__ boffs, int* __restrict__ offs,
                        float* __restrict__ deginv, int* __restrict__ srow,
                        int n, int bspan) {
    __shared__ int cnt[NBUCK];
    __shared__ int cur[NBUCK];
    __shared__ int wsum[4];
    const int b = blockIdx.x, tid = threadIdx.x;
    const int start = boffs[b], end = boffs[b + 1];
    cnt[tid] = 0;
    __syncthreads();
    for (int i = start + tid; i < end; i += 256)
        atomicAdd(&cnt[ebuf[i] >> 16], 1);
    __syncthreads();
    const int v = cnt[tid];
    const int lane = tid & 63, wid = tid >> 6;
    int ps = v;
#pragma unroll
    for (int off = 1; off < 64; off <<= 1) {
        int t = __shfl_up(ps, off);
        if (lane >= off) ps += t;
    }
    if (lane == 63) wsum[wid] = ps;
    __syncthreads();
    int wb = 0;
    for (int w = 0; w < wid; ++w) wb += wsum[w];
    const int excl = start + wb + ps - v;
    const int node = b * bspan + tid;
    if (tid < bspan && node < n) {
        offs[node] = excl;
        deginv[node] = 1.0f / (float)(v + 1);
    }
    cur[tid] = excl;
    __syncthreads();
    for (int i = start + tid; i < end; i += 256) {
        const unsigned u = ebuf[i];
        const int pos = atomicAdd(&cur[u >> 16], 1);
        srow[pos] = (int)(u & 0xFFFFu);
    }
}

// ---------------- gather (bf16 in/out, fp32 accum) ----------------
__global__ __launch_bounds__(256, 8)
void k_gather_bf(const uint2* __restrict__ xb, const int* __restrict__ offs,
                 const int* __restrict__ srow, const float* __restrict__ deginv,
                 uint2* __restrict__ aggb, int n) {
    const int node = blockIdx.x * 8 + (threadIdx.x >> 5);
    const int lane = threadIdx.x & 31;
    if (node >= n) return;
    const size_t rb = (size_t)node * 32 + lane;
    uint2 sv = xb[rb];
    float a0 = blo(sv.x), a1 = bhi(sv.x), a2 = blo(sv.y), a3 = bhi(sv.y);
    const int s = offs[node], e = offs[node + 1];
    int p = s;
    for (; p + 4 <= e; p += 4) {
        const int r0 = srow[p], r1 = srow[p + 1], r2 = srow[p + 2], r3 = srow[p + 3];
        const uint2 v0 = xb[(size_t)r0 * 32 + lane];
        const uint2 v1 = xb[(size_t)r1 * 32 + lane];
        const uint2 v2 = xb[(size_t)r2 * 32 + lane];
        const uint2 v3 = xb[(size_t)r3 * 32 + lane];
        a0 += (blo(v0.x) + blo(v1.x)) + (blo(v2.x) + blo(v3.x));
        a1 += (bhi(v0.x) + bhi(v1.x)) + (bhi(v2.x) + bhi(v3.x));
        a2 += (blo(v0.y) + blo(v1.y)) + (blo(v2.y) + blo(v3.y));
        a3 += (bhi(v0.y) + bhi(v1.y)) + (bhi(v2.y) + bhi(v3.y));
    }
    for (; p < e; ++p) {
        const uint2 v = xb[(size_t)srow[p] * 32 + lane];
        a0 += blo(v.x); a1 += bhi(v.x); a2 += blo(v.y); a3 += bhi(v.y);
    }
    const float w = deginv[node];
    uint2 o;
    o.x = (unsigned)f2bf(a0 * w) | ((unsigned)f2bf(a1 * w) << 16);
    o.y = (unsigned)f2bf(a2 * w) | ((unsigned)f2bf(a3 * w) << 16);
    aggb[rb] = o;
}

// ---------------- MFMA GEMM (layers 1,2): Y = relu([agg|X]@[Wo;Wr]+b) -------
__global__ __launch_bounds__(256, 2)
void k_gemm_mfma(const unsigned short* __restrict__ aggb,
                 const unsigned short* __restrict__ xb,
                 const uint4* __restrict__ wfrag, const float* __restrict__ bvec,
                 unsigned short* __restrict__ y, int n) {
    const int tid = threadIdx.x;
    const int w = tid >> 6, L = tid & 63;
    const int quad = L >> 4, l15 = L & 15;
    const int m0 = blockIdx.x * 64;

    bf16x8 bfr[8][2];
#pragma unroll
    for (int t = 0; t < 8; ++t)
#pragma unroll
        for (int u = 0; u < 2; ++u)
            bfr[t][u] = *(const bf16x8*)&wfrag[(size_t)((t * 8 + (w * 2 + u)) * 64 + L)];

    f32x4 acc[4][2];
#pragma unroll
    for (int mt = 0; mt < 4; ++mt)
#pragma unroll
        for (int u = 0; u < 2; ++u)
            acc[mt][u] = (f32x4){0.f, 0.f, 0.f, 0.f};

    const bf16x8 zf = {0, 0, 0, 0, 0, 0, 0, 0};
#pragma unroll
    for (int t = 0; t < 8; ++t) {
        const unsigned short* Ab = (t < 4) ? aggb : xb;
        const int koff = (t & 3) * 32 + quad * 8;
        bf16x8 af[4];
#pragma unroll
        for (int mt = 0; mt < 4; ++mt) {
            const int r = m0 + mt * 16 + l15;
            af[mt] = (r < n) ? *(const bf16x8*)(Ab + (size_t)r * 128 + koff) : zf;
        }
#pragma unroll
        for (int mt = 0; mt < 4; ++mt)
#pragma unroll
            for (int u = 0; u < 2; ++u)
                acc[mt][u] = __builtin_amdgcn_mfma_f32_16x16x32_bf16(
                    af[mt], bfr[t][u], acc[mt][u], 0, 0, 0);
    }

    float bb[2];
    bb[0] = bvec[w * 32 + l15];
    bb[1] = bvec[w * 32 + 16 + l15];
#pragma unroll
    for (int mt = 0; mt < 4; ++mt)
#pragma unroll
        for (int u = 0; u < 2; ++u)
#pragma unroll
            for (int r4 = 0; r4 < 4; ++r4) {
                const int r = m0 + mt * 16 + quad * 4 + r4;
                if (r < n) {
                    float v = fmaxf(acc[mt][u][r4] + bb[u], 0.f);
                    y[(size_t)r * 128 + w * 32 + u * 16 + l15] = f2bf(v);
                }
            }
}

// ---------------- layer 3: MFMA GEMM (DOUT=64) + relu + log_softmax ---------
__global__ __launch_bounds__(256, 2)
void k_gemm3_mfma(const unsigned short* __restrict__ aggb,
                  const unsigned short* __restrict__ xb,
                  const uint4* __restrict__ wfrag, const float* __restrict__ bvec,
                  float* __restrict__ out, int n) {
    const int tid = threadIdx.x;
    const int w = tid >> 6, L = tid & 63;
    const int quad = L >> 4, l15 = L & 15;
    const int whalf = w & 1;
    const int m0 = blockIdx.x * 128 + (w >> 1) * 64;

    bf16x8 bfr[8][2];
#pragma unroll
    for (int t = 0; t < 8; ++t)
#pragma unroll
        for (int u = 0; u < 2; ++u)
            bfr[t][u] = *(const bf16x8*)&wfrag[(size_t)((t * 4 + (whalf * 2 + u)) * 64 + L)];

    f32x4 acc[4][2];
#pragma unroll
    for (int mt = 0; mt < 4; ++mt)
#pragma unroll
        for (int u = 0; u < 2; ++u)
            acc[mt][u] = (f32x4){0.f, 0.f, 0.f, 0.f};

    const bf16x8 zf = {0, 0, 0, 0, 0, 0, 0, 0};
#pragma unroll
    for (int t = 0; t < 8; ++t) {
        const unsigned short* Ab = (t < 4) ? aggb : xb;
        const int koff = (t & 3) * 32 + quad * 8;
        bf16x8 af[4];
#pragma unroll
        for (int mt = 0; mt < 4; ++mt) {
            const int r = m0 + mt * 16 + l15;
            af[mt] = (r < n) ? *(const bf16x8*)(Ab + (size_t)r * 128 + koff) : zf;
        }
#pragma unroll
        for (int mt = 0; mt < 4; ++mt)
#pragma unroll
            for (int u = 0; u < 2; ++u)
                acc[mt][u] = __builtin_amdgcn_mfma_f32_16x16x32_bf16(
                    af[mt], bfr[t][u], acc[mt][u], 0, 0, 0);
    }

    float bb[2];
    bb[0] = bvec[whalf * 32 + l15];
    bb[1] = bvec[whalf * 32 + 16 + l15];
#pragma unroll
    for (int mt = 0; mt < 4; ++mt)
#pragma unroll
        for (int u = 0; u < 2; ++u)
#pragma unroll
            for (int r4 = 0; r4 < 4; ++r4)
                acc[mt][u][r4] = fmaxf(acc[mt][u][r4] + bb[u], 0.f);

    __shared__ float pm[128][2];
    __shared__ float ps[128][2];
    const int rlb = (w >> 1) * 64;

#pragma unroll
    for (int mt = 0; mt < 4; ++mt)
#pragma unroll
        for (int r4 = 0; r4 < 4; ++r4) {
            float p = fmaxf(acc[mt][0][r4], acc[mt][1][r4]);
            p = fmaxf(p, __shfl_xor(p, 1));
            p = fmaxf(p, __shfl_xor(p, 2));
            p = fmaxf(p, __shfl_xor(p, 4));
            p = fmaxf(p, __shfl_xor(p, 8));
            if (l15 == 0) pm[rlb + mt * 16 + quad * 4 + r4][whalf] = p;
        }
    __syncthreads();

#pragma unroll
    for (int mt = 0; mt < 4; ++mt)
#pragma unroll
        for (int r4 = 0; r4 < 4; ++r4) {
            const int rl = rlb + mt * 16 + quad * 4 + r4;
            const float M = fmaxf(pm[rl][0], pm[rl][1]);
            float s = __expf(acc[mt][0][r4] - M) + __expf(acc[mt][1][r4] - M);
            s += __shfl_xor(s, 1);
            s += __shfl_xor(s, 2);
            s += __shfl_xor(s, 4);
            s += __shfl_xor(s, 8);
            if (l15 == 0) ps[rl][whalf] = s;
        }
    __syncthreads();

#pragma unroll
    for (int mt = 0; mt < 4; ++mt)
#pragma unroll
        for (int r4 = 0; r4 < 4; ++r4) {
            const int rl = rlb + mt * 16 + quad * 4 + r4;
            const int r = blockIdx.x * 128 + rl;
            const float M = fmaxf(pm[rl][0], pm[rl][1]);
            const float lse = M + __logf(ps[rl][0] + ps[rl][1]);
            if (r < n) {
#pragma unroll
                for (int u = 0; u < 2; ++u)
                    out[(size_t)r * 64 + whalf * 32 + u * 16 + l15] =
                        acc[mt][u][r4] - lse;
            }
        }
}

extern "C" void kernel_launch(void* const* d_in, const int* in_sizes, int n_in,
                              void* d_out, int out_size, void* d_ws, size_t ws_size,
                              hipStream_t stream) {
    const float* x   = (const float*)d_in[0];
    const int*   ei  = (const int*)d_in[1];
    const float* W1o = (const float*)d_in[2];
    const float* b1  = (const float*)d_in[3];
    const float* W1r = (const float*)d_in[4];
    const float* W2o = (const float*)d_in[5];
    const float* b2  = (const float*)d_in[6];
    const float* W2r = (const float*)d_in[7];
    const float* W3o = (const float*)d_in[8];
    const float* b3  = (const float*)d_in[9];
    const float* W3r = (const float*)d_in[10];

    const int N = in_sizes[0] / DK;   // 50000 (row index must fit 16 bits)
    const int E = in_sizes[1] / 2;    // 800000
    const int* row = ei;
    const int* col = ei + E;
    const int bspan = (N + NBUCK - 1) / NBUCK;   // 196 (<256, fits 8 bits)

    // workspace (4-byte units; 800 ints of bucket state keeps 16B alignment)
    int*   bhist  = (int*)d_ws;                         // 256
    int*   boffs  = bhist + 256;                        // 257 (pad 288)
    int*   bcur   = boffs + 288;                        // 256
    int*   offs   = bcur + 256;                         // N+1
    float* deginv = (float*)(offs + ((N + 64) & ~63)); // N
    int*   srow   = (int*)(deginv + ((N + 63) & ~63)); // E
    unsigned int* ebuf = (unsigned int*)(srow + ((E + 63) & ~63)); // E
    uint4* wf1    = (uint4*)(ebuf + ((E + 63) & ~63)); // 4096 uint4
    uint4* wf2    = wf1 + 4096;                        // 4096
    uint4* wf3    = wf2 + 4096;                        // 2048
    unsigned short* xbuf = (unsigned short*)(wf3 + 2048);   // N*128 bf16
    unsigned short* aggb = xbuf + (size_t)N * 128;          // N*128
    unsigned short* Ya   = aggb + (size_t)N * 128;          // N*128
    float* out = (float*)d_out;

    // prep: x->bf16 (also zero-inits bhist), weights->frag layout
    const int n4 = N * 32;
    k_cvtx<<<(n4 + 255) / 256, 256, 0, stream>>>((const float4*)x, (uint2*)xbuf, bhist, n4);
    k_wprep<<<16, 256, 0, stream>>>(W1o, W1r, wf1, 128);
    k_wprep<<<16, 256, 0, stream>>>(W2o, W2r, wf2, 128);
    k_wprep<<<8, 256, 0, stream>>>(W3o, W3r, wf3, 64);

    // CSR build: counting sort
    k_bhist<<<400, 256, 0, stream>>>(col, bhist, E, bspan);
    k_bscan<<<1, 256, 0, stream>>>(bhist, boffs, bcur, offs, N, E);
    k_part<<<(E + 4095) / 4096, 256, 0, stream>>>(row, col, bcur, ebuf, E, bspan);
    k_fillb<<<NBUCK, 256, 0, stream>>>(ebuf, boffs, offs, deginv, srow, N, bspan);

    const int Gg = (N + 7) / 8;
    const int Gm = (N + 63) / 64;
    const int G3 = (N + 127) / 128;

    // layer 1: xbuf -> aggb -> Ya
    k_gather_bf<<<Gg, 256, 0, stream>>>((const uint2*)xbuf, offs, srow, deginv, (uint2*)aggb, N);
    k_gemm_mfma<<<Gm, 256, 0, stream>>>(aggb, xbuf, wf1, b1, Ya, N);
    // layer 2: Ya -> aggb -> xbuf
    k_gather_bf<<<Gg, 256, 0, stream>>>((const uint2*)Ya, offs, srow, deginv, (uint2*)aggb, N);
    k_gemm_mfma<<<Gm, 256, 0, stream>>>(aggb, Ya, wf2, b2, xbuf, N);
    // layer 3: xbuf -> aggb -> out (fp32 + log_softmax)
    k_gather_bf<<<Gg, 256, 0, stream>>>((const uint2*)xbuf, offs, srow, deginv, (uint2*)aggb, N);
    k_gemm3_mfma<<<G3, 256, 0, stream>>>(aggb, xbuf, wf3, b3, out, N);
}

// Round 8
// 277.215 us; speedup vs baseline: 2.7310x; 1.0643x over previous
//
#include <hip/hip_runtime.h>
#include <math.h>

// ClusterGCN 3-layer inference, MI355X — R8.
// R7 post-mortem: CSR build fixed; gathers now dominate (8B/lane loads).
// R8: (1) gather at 16B/lane (uint4, 16 lanes/node, 4 nodes/wave);
//     (2) layer 3 commuted: H=X@W3o, R=X@W3r+b3 first (MFMA), then fused
//         gather(H)+R+relu+log_softmax — halves layer-3 random bytes;
//     (3) GEMM launch_bounds min-waves 2->3.

constexpr int DK = 128;
constexpr int NBUCK = 256;

typedef __attribute__((ext_vector_type(8))) short bf16x8;
typedef __attribute__((ext_vector_type(4))) float f32x4;

__device__ inline unsigned short f2bf(float f) {
    unsigned int u; __builtin_memcpy(&u, &f, 4);
    unsigned int r = (u + 0x7FFFu + ((u >> 16) & 1u)) >> 16;
    return (unsigned short)r;
}
__device__ inline float blo(unsigned int u) {
    unsigned int t = u << 16; float f; __builtin_memcpy(&f, &t, 4); return f;
}
__device__ inline float bhi(unsigned int u) {
    unsigned int t = u & 0xffff0000u; float f; __builtin_memcpy(&f, &t, 4); return f;
}

// ---------------- fp32 -> bf16 convert (x); block 0 also zeroes bhist -------
__global__ void k_cvtx(const float4* __restrict__ x, uint2* __restrict__ xb,
                       int* __restrict__ bhist, int n4) {
    if (blockIdx.x == 0) bhist[threadIdx.x] = 0;
    int i = blockIdx.x * 256 + threadIdx.x;
    if (i >= n4) return;
    float4 v = x[i];
    uint2 o;
    o.x = (unsigned)f2bf(v.x) | ((unsigned)f2bf(v.y) << 16);
    o.y = (unsigned)f2bf(v.z) | ((unsigned)f2bf(v.w) << 16);
    xb[i] = o;
}

// ---------------- weight prep: swizzle [Wout;Wroot] into B-frag layout ------
__global__ void k_wprep(const float* __restrict__ Wout, const float* __restrict__ Wroot,
                        uint4* __restrict__ frag, int dout) {
    int tid = blockIdx.x * 256 + threadIdx.x;
    int total = 8 * (dout >> 4) * 64;
    if (tid >= total) return;
    int L = tid & 63;
    int fu = (tid >> 6) % (dout >> 4);
    int t = (tid >> 6) / (dout >> 4);
    int quad = L >> 4, l15 = L & 15;
    int n = fu * 16 + l15;
    unsigned int p[4];
#pragma unroll
    for (int jj = 0; jj < 4; ++jj) {
        int k0 = t * 32 + quad * 8 + jj * 2;
        float v0 = (k0 < 128) ? Wout[k0 * dout + n] : Wroot[(k0 - 128) * dout + n];
        int k1 = k0 + 1;
        float v1 = (k1 < 128) ? Wout[k1 * dout + n] : Wroot[(k1 - 128) * dout + n];
        p[jj] = (unsigned)f2bf(v0) | ((unsigned)f2bf(v1) << 16);
    }
    frag[tid] = make_uint4(p[0], p[1], p[2], p[3]);
}

// ---------------- CSR build: two-level counting sort (R7, unchanged) --------
__global__ void k_bhist(const int* __restrict__ col, int* __restrict__ bhist,
                        int e, int bspan) {
    __shared__ int h[NBUCK];
    h[threadIdx.x] = 0;
    __syncthreads();
    for (int i = blockIdx.x * blockDim.x + threadIdx.x; i < e;
         i += gridDim.x * blockDim.x)
        atomicAdd(&h[col[i] / bspan], 1);
    __syncthreads();
    int v = h[threadIdx.x];
    if (v) atomicAdd(&bhist[threadIdx.x], v);
}

__global__ void k_bscan(const int* __restrict__ bhist, int* __restrict__ boffs,
                        int* __restrict__ bcur, int* __restrict__ offs,
                        int n, int e) {
    __shared__ int wsum[4];
    const int tid = threadIdx.x, lane = tid & 63, wid = tid >> 6;
    int v = bhist[tid];
    int ps = v;
#pragma unroll
    for (int off = 1; off < 64; off <<= 1) {
        int t = __shfl_up(ps, off);
        if (lane >= off) ps += t;
    }
    if (lane == 63) wsum[wid] = ps;
    __syncthreads();
    int wb = 0;
    for (int w = 0; w < wid; ++w) wb += wsum[w];
    int excl = wb + ps - v;
    boffs[tid] = excl;
    bcur[tid] = excl;
    if (tid == 255) boffs[256] = excl + v;
    if (tid == 0) offs[n] = e;
}

__global__ void k_part(const int* __restrict__ row, const int* __restrict__ col,
                       int* __restrict__ bcur, unsigned int* __restrict__ ebuf,
                       int e, int bspan) {
    __shared__ int cnt[NBUCK];
    __shared__ int base[NBUCK];
    const int tid = threadIdx.x;
    const int t0 = blockIdx.x * 4096;
    cnt[tid] = 0;
    __syncthreads();
    int bk[16];
#pragma unroll
    for (int k = 0; k < 16; ++k) {
        int i = t0 + k * 256 + tid;
        int b = -1;
        if (i < e) { b = col[i] / bspan; atomicAdd(&cnt[b], 1); }
        bk[k] = b;
    }
    __syncthreads();
    base[tid] = cnt[tid] ? atomicAdd(&bcur[tid], cnt[tid]) : 0;
    cnt[tid] = 0;
    __syncthreads();
#pragma unroll
    for (int k = 0; k < 16; ++k) {
        int i = t0 + k * 256 + tid;
        if (i < e) {
            int b = bk[k];
            int slot = base[b] + atomicAdd(&cnt[b], 1);
            unsigned int colofs = (unsigned)(col[i] - b * bspan);
            ebuf[slot] = ((unsigned)row[i] & 0xFFFFu) | (colofs << 16);
        }
    }
}

__global__ void k_fillb(const unsigned int* __restrict__ ebuf,
                        const int* __restrict__ boffs, int* __restrict__ offs,
                        float* __restrict__ deginv, int* __restrict__ srow,
                        int n, int bspan) {
    __shared__ int cnt[NBUCK];
    __shared__ int cur[NBUCK];
    __shared__ int wsum[4];
    const int b = blockIdx.x, tid = threadIdx.x;
    const int start = boffs[b], end = boffs[b + 1];
    cnt[tid] = 0;
    __syncthreads();
    for (int i = start + tid; i < end; i += 256)
        atomicAdd(&cnt[ebuf[i] >> 16], 1);
    __syncthreads();
    const int v = cnt[tid];
    const int lane = tid & 63, wid = tid >> 6;
    int ps = v;
#pragma unroll
    for (int off = 1; off < 64; off <<= 1) {
        int t = __shfl_up(ps, off);
        if (lane >= off) ps += t;
    }
    if (lane == 63) wsum[wid] = ps;
    __syncthreads();
    int wb = 0;
    for (int w = 0; w < wid; ++w) wb += wsum[w];
    const int excl = start + wb + ps - v;
    const int node = b * bspan + tid;
    if (tid < bspan && node < n) {
        offs[node] = excl;
        deginv[node] = 1.0f / (float)(v + 1);
    }
    cur[tid] = excl;
    __syncthreads();
    for (int i = start + tid; i < end; i += 256) {
        const unsigned u = ebuf[i];
        const int pos = atomicAdd(&cur[u >> 16], 1);
        srow[pos] = (int)(u & 0xFFFFu);
    }
}

// ---------------- gather, 16 lanes/node, uint4 (16B) loads ----------------
__global__ __launch_bounds__(256, 8)
void k_gather16(const uint4* __restrict__ xb, const int* __restrict__ offs,
                const int* __restrict__ srow, const float* __restrict__ deginv,
                uint4* __restrict__ aggb, int n) {
    const int node = blockIdx.x * 16 + (threadIdx.x >> 4);
    const int lane = threadIdx.x & 15;
    if (node >= n) return;
    const size_t rb = (size_t)node * 16 + lane;   // row = 16 uint4
    uint4 sv = xb[rb];
    float a0 = blo(sv.x), a1 = bhi(sv.x), a2 = blo(sv.y), a3 = bhi(sv.y);
    float a4 = blo(sv.z), a5 = bhi(sv.z), a6 = blo(sv.w), a7 = bhi(sv.w);
    const int s = offs[node], e = offs[node + 1];
    int p = s;
    for (; p + 4 <= e; p += 4) {
        const int r0 = srow[p], r1 = srow[p + 1], r2 = srow[p + 2], r3 = srow[p + 3];
        const uint4 v0 = xb[(size_t)r0 * 16 + lane];
        const uint4 v1 = xb[(size_t)r1 * 16 + lane];
        const uint4 v2 = xb[(size_t)r2 * 16 + lane];
        const uint4 v3 = xb[(size_t)r3 * 16 + lane];
        a0 += (blo(v0.x) + blo(v1.x)) + (blo(v2.x) + blo(v3.x));
        a1 += (bhi(v0.x) + bhi(v1.x)) + (bhi(v2.x) + bhi(v3.x));
        a2 += (blo(v0.y) + blo(v1.y)) + (blo(v2.y) + blo(v3.y));
        a3 += (bhi(v0.y) + bhi(v1.y)) + (bhi(v2.y) + bhi(v3.y));
        a4 += (blo(v0.z) + blo(v1.z)) + (blo(v2.z) + blo(v3.z));
        a5 += (bhi(v0.z) + bhi(v1.z)) + (bhi(v2.z) + bhi(v3.z));
        a6 += (blo(v0.w) + blo(v1.w)) + (blo(v2.w) + blo(v3.w));
        a7 += (bhi(v0.w) + bhi(v1.w)) + (bhi(v2.w) + bhi(v3.w));
    }
    for (; p < e; ++p) {
        const uint4 v = xb[(size_t)srow[p] * 16 + lane];
        a0 += blo(v.x); a1 += bhi(v.x); a2 += blo(v.y); a3 += bhi(v.y);
        a4 += blo(v.z); a5 += bhi(v.z); a6 += blo(v.w); a7 += bhi(v.w);
    }
    const float w = deginv[node];
    uint4 o;
    o.x = (unsigned)f2bf(a0 * w) | ((unsigned)f2bf(a1 * w) << 16);
    o.y = (unsigned)f2bf(a2 * w) | ((unsigned)f2bf(a3 * w) << 16);
    o.z = (unsigned)f2bf(a4 * w) | ((unsigned)f2bf(a5 * w) << 16);
    o.w = (unsigned)f2bf(a6 * w) | ((unsigned)f2bf(a7 * w) << 16);
    aggb[rb] = o;
}

// ---------------- MFMA GEMM (layers 1,2): Y = relu([agg|X]@[Wo;Wr]+b) -------
__global__ __launch_bounds__(256, 3)
void k_gemm_mfma(const unsigned short* __restrict__ aggb,
                 const unsigned short* __restrict__ xb,
                 const uint4* __restrict__ wfrag, const float* __restrict__ bvec,
                 unsigned short* __restrict__ y, int n) {
    const int tid = threadIdx.x;
    const int w = tid >> 6, L = tid & 63;
    const int quad = L >> 4, l15 = L & 15;
    const int m0 = blockIdx.x * 64;

    bf16x8 bfr[8][2];
#pragma unroll
    for (int t = 0; t < 8; ++t)
#pragma unroll
        for (int u = 0; u < 2; ++u)
            bfr[t][u] = *(const bf16x8*)&wfrag[(size_t)((t * 8 + (w * 2 + u)) * 64 + L)];

    f32x4 acc[4][2];
#pragma unroll
    for (int mt = 0; mt < 4; ++mt)
#pragma unroll
        for (int u = 0; u < 2; ++u)
            acc[mt][u] = (f32x4){0.f, 0.f, 0.f, 0.f};

    const bf16x8 zf = {0, 0, 0, 0, 0, 0, 0, 0};
#pragma unroll
    for (int t = 0; t < 8; ++t) {
        const unsigned short* Ab = (t < 4) ? aggb : xb;
        const int koff = (t & 3) * 32 + quad * 8;
        bf16x8 af[4];
#pragma unroll
        for (int mt = 0; mt < 4; ++mt) {
            const int r = m0 + mt * 16 + l15;
            af[mt] = (r < n) ? *(const bf16x8*)(Ab + (size_t)r * 128 + koff) : zf;
        }
#pragma unroll
        for (int mt = 0; mt < 4; ++mt)
#pragma unroll
            for (int u = 0; u < 2; ++u)
                acc[mt][u] = __builtin_amdgcn_mfma_f32_16x16x32_bf16(
                    af[mt], bfr[t][u], acc[mt][u], 0, 0, 0);
    }

    float bb[2];
    bb[0] = bvec[w * 32 + l15];
    bb[1] = bvec[w * 32 + 16 + l15];
#pragma unroll
    for (int mt = 0; mt < 4; ++mt)
#pragma unroll
        for (int u = 0; u < 2; ++u)
#pragma unroll
            for (int r4 = 0; r4 < 4; ++r4) {
                const int r = m0 + mt * 16 + quad * 4 + r4;
                if (r < n) {
                    float v = fmaxf(acc[mt][u][r4] + bb[u], 0.f);
                    y[(size_t)r * 128 + w * 32 + u * 16 + l15] = f2bf(v);
                }
            }
}

// ---------------- layer 3 producer: H = X@W3o (bf16), R = X@W3r + b3 (fp32) -
// Block = 4 waves, M-tile 64; wave w owns cols w*16..w*16+16 (u=w).
__global__ __launch_bounds__(256, 3)
void k_gemm3hr(const unsigned short* __restrict__ xb,
               const uint4* __restrict__ wfrag, const float* __restrict__ bvec,
               unsigned short* __restrict__ H, float* __restrict__ R, int n) {
    const int tid = threadIdx.x;
    const int w = tid >> 6, L = tid & 63;
    const int quad = L >> 4, l15 = L & 15;
    const int m0 = blockIdx.x * 64;

    bf16x8 bo[4], br[4];
#pragma unroll
    for (int t = 0; t < 4; ++t) {
        bo[t] = *(const bf16x8*)&wfrag[(size_t)((t * 4 + w) * 64 + L)];
        br[t] = *(const bf16x8*)&wfrag[(size_t)(((t + 4) * 4 + w) * 64 + L)];
    }

    f32x4 accH[4], accR[4];
#pragma unroll
    for (int mt = 0; mt < 4; ++mt) {
        accH[mt] = (f32x4){0.f, 0.f, 0.f, 0.f};
        accR[mt] = (f32x4){0.f, 0.f, 0.f, 0.f};
    }

    const bf16x8 zf = {0, 0, 0, 0, 0, 0, 0, 0};
#pragma unroll
    for (int t = 0; t < 4; ++t) {
        const int koff = t * 32 + quad * 8;
        bf16x8 af[4];
#pragma unroll
        for (int mt = 0; mt < 4; ++mt) {
            const int r = m0 + mt * 16 + l15;
            af[mt] = (r < n) ? *(const bf16x8*)(xb + (size_t)r * 128 + koff) : zf;
        }
#pragma unroll
        for (int mt = 0; mt < 4; ++mt) {
            accH[mt] = __builtin_amdgcn_mfma_f32_16x16x32_bf16(af[mt], bo[t], accH[mt], 0, 0, 0);
            accR[mt] = __builtin_amdgcn_mfma_f32_16x16x32_bf16(af[mt], br[t], accR[mt], 0, 0, 0);
        }
    }

    const float bb = bvec[w * 16 + l15];
#pragma unroll
    for (int mt = 0; mt < 4; ++mt)
#pragma unroll
        for (int r4 = 0; r4 < 4; ++r4) {
            const int r = m0 + mt * 16 + quad * 4 + r4;
            if (r < n) {
                H[(size_t)r * 64 + w * 16 + l15] = f2bf(accH[mt][r4]);
                R[(size_t)r * 64 + w * 16 + l15] = accR[mt][r4] + bb;
            }
        }
}

// ---------------- layer 3 fused: gather(H)+R, relu, log_softmax ----------------
// 16 lanes/node (uint2 of H = 4 cols, float4 of R), 16 nodes/block.
__global__ __launch_bounds__(256, 8)
void k_gather3(const uint2* __restrict__ Hb, const float4* __restrict__ R4,
               const int* __restrict__ offs, const int* __restrict__ srow,
               const float* __restrict__ deginv, float4* __restrict__ out, int n) {
    const int node = blockIdx.x * 16 + (threadIdx.x >> 4);
    const int lane = threadIdx.x & 15;
    if (node >= n) return;
    const size_t rb = (size_t)node * 16 + lane;   // row = 16 uint2 / 16 float4
    uint2 sv = Hb[rb];
    float a0 = blo(sv.x), a1 = bhi(sv.x), a2 = blo(sv.y), a3 = bhi(sv.y);
    const int s = offs[node], e = offs[node + 1];
    int p = s;
    for (; p + 4 <= e; p += 4) {
        const int r0 = srow[p], r1 = srow[p + 1], r2 = srow[p + 2], r3 = srow[p + 3];
        const uint2 v0 = Hb[(size_t)r0 * 16 + lane];
        const uint2 v1 = Hb[(size_t)r1 * 16 + lane];
        const uint2 v2 = Hb[(size_t)r2 * 16 + lane];
        const uint2 v3 = Hb[(size_t)r3 * 16 + lane];
        a0 += (blo(v0.x) + blo(v1.x)) + (blo(v2.x) + blo(v3.x));
        a1 += (bhi(v0.x) + bhi(v1.x)) + (bhi(v2.x) + bhi(v3.x));
        a2 += (blo(v0.y) + blo(v1.y)) + (blo(v2.y) + blo(v3.y));
        a3 += (bhi(v0.y) + bhi(v1.y)) + (bhi(v2.y) + bhi(v3.y));
    }
    for (; p < e; ++p) {
        const uint2 v = Hb[(size_t)srow[p] * 16 + lane];
        a0 += blo(v.x); a1 += bhi(v.x); a2 += blo(v.y); a3 += bhi(v.y);
    }
    const float w = deginv[node];
    const float4 r = R4[rb];
    float v0 = fmaxf(a0 * w + r.x, 0.f);
    float v1 = fmaxf(a1 * w + r.y, 0.f);
    float v2 = fmaxf(a2 * w + r.z, 0.f);
    float v3 = fmaxf(a3 * w + r.w, 0.f);
    float m = fmaxf(fmaxf(v0, v1), fmaxf(v2, v3));
    m = fmaxf(m, __shfl_xor(m, 1));
    m = fmaxf(m, __shfl_xor(m, 2));
    m = fmaxf(m, __shfl_xor(m, 4));
    m = fmaxf(m, __shfl_xor(m, 8));
    float s2 = __expf(v0 - m) + __expf(v1 - m) + __expf(v2 - m) + __expf(v3 - m);
    s2 += __shfl_xor(s2, 1);
    s2 += __shfl_xor(s2, 2);
    s2 += __shfl_xor(s2, 4);
    s2 += __shfl_xor(s2, 8);
    const float lse = m + __logf(s2);
    out[rb] = make_float4(v0 - lse, v1 - lse, v2 - lse, v3 - lse);
}

extern "C" void kernel_launch(void* const* d_in, const int* in_sizes, int n_in,
                              void* d_out, int out_size, void* d_ws, size_t ws_size,
                              hipStream_t stream) {
    const float* x   = (const float*)d_in[0];
    const int*   ei  = (const int*)d_in[1];
    const float* W1o = (const float*)d_in[2];
    const float* b1  = (const float*)d_in[3];
    const float* W1r = (const float*)d_in[4];
    const float* W2o = (const float*)d_in[5];
    const float* b2  = (const float*)d_in[6];
    const float* W2r = (const float*)d_in[7];
    const float* W3o = (const float*)d_in[8];
    const float* b3  = (const float*)d_in[9];
    const float* W3r = (const float*)d_in[10];

    const int N = in_sizes[0] / DK;   // 50000 (row index fits 16 bits)
    const int E = in_sizes[1] / 2;    // 800000
    const int* row = ei;
    const int* col = ei + E;
    const int bspan = (N + NBUCK - 1) / NBUCK;   // 196

    int*   bhist  = (int*)d_ws;                         // 256
    int*   boffs  = bhist + 256;                        // 257 (pad 288)
    int*   bcur   = boffs + 288;                        // 256
    int*   offs   = bcur + 256;                         // N+1
    float* deginv = (float*)(offs + ((N + 64) & ~63));  // N
    int*   srow   = (int*)(deginv + ((N + 63) & ~63));  // E
    unsigned int* ebuf = (unsigned int*)(srow + ((E + 63) & ~63)); // E
    uint4* wf1    = (uint4*)(ebuf + ((E + 63) & ~63));  // 4096 uint4
    uint4* wf2    = wf1 + 4096;                         // 4096
    uint4* wf3    = wf2 + 4096;                         // 2048
    unsigned short* xbuf = (unsigned short*)(wf3 + 2048);   // N*128 bf16
    unsigned short* aggb = xbuf + (size_t)N * 128;          // N*128 (also H)
    unsigned short* Ya   = aggb + (size_t)N * 128;          // N*128 (also R fp32 N*64)
    float* out = (float*)d_out;

    const int n4 = N * 32;
    k_cvtx<<<(n4 + 255) / 256, 256, 0, stream>>>((const float4*)x, (uint2*)xbuf, bhist, n4);
    k_wprep<<<16, 256, 0, stream>>>(W1o, W1r, wf1, 128);
    k_wprep<<<16, 256, 0, stream>>>(W2o, W2r, wf2, 128);
    k_wprep<<<8, 256, 0, stream>>>(W3o, W3r, wf3, 64);

    k_bhist<<<400, 256, 0, stream>>>(col, bhist, E, bspan);
    k_bscan<<<1, 256, 0, stream>>>(bhist, boffs, bcur, offs, N, E);
    k_part<<<(E + 4095) / 4096, 256, 0, stream>>>(row, col, bcur, ebuf, E, bspan);
    k_fillb<<<NBUCK, 256, 0, stream>>>(ebuf, boffs, offs, deginv, srow, N, bspan);

    const int Gg = (N + 15) / 16;      // gather grids (16 nodes/block)
    const int Gm = (N + 63) / 64;      // gemm grid

    // layer 1: xbuf -> aggb -> Ya
    k_gather16<<<Gg, 256, 0, stream>>>((const uint4*)xbuf, offs, srow, deginv, (uint4*)aggb, N);
    k_gemm_mfma<<<Gm, 256, 0, stream>>>(aggb, xbuf, wf1, b1, Ya, N);
    // layer 2: Ya -> aggb -> xbuf
    k_gather16<<<Gg, 256, 0, stream>>>((const uint4*)Ya, offs, srow, deginv, (uint4*)aggb, N);
    k_gemm_mfma<<<Gm, 256, 0, stream>>>(aggb, Ya, wf2, b2, xbuf, N);
    // layer 3: H=xbuf@W3o (->aggb), R=xbuf@W3r+b3 (->Ya as fp32), then fused
    // gather(H)+R+relu+log_softmax -> out
    k_gemm3hr<<<Gm, 256, 0, stream>>>(xbuf, wf3, b3, aggb, (float*)Ya, N);
    k_gather3<<<Gg, 256, 0, stream>>>((const uint2*)aggb, (const float4*)Ya,
                                      offs, srow, deginv, (float4*)out, N);
}